// Round 4
// baseline (701.053 us; speedup 1.0000x reference)
//
#include <hip/hip_runtime.h>

#define NN 50000
#define NE 800000
#define MPAD 50048   // 782 * 64
#define SCAN_BLK 512
#define SCAN_NB 98   // ceil(NN/512)

typedef __attribute__((ext_vector_type(8))) short short8;
typedef __attribute__((ext_vector_type(4))) float f32x4;

__device__ __forceinline__ ushort f2b(float f) {
    uint u = __builtin_bit_cast(uint, f);
    uint r = (u + 0x7fffu + ((u >> 16) & 1u)) >> 16;
    return (ushort)r;
}
__device__ __forceinline__ float blo(uint u) { return __builtin_bit_cast(float, u << 16); }
__device__ __forceinline__ float bhi(uint u) { return __builtin_bit_cast(float, u & 0xffff0000u); }

// ---------------- CSR build ----------------

__global__ void k_deg(const int* __restrict__ dst, int* __restrict__ deg, int e) {
    int i = blockIdx.x * blockDim.x + threadIdx.x;
    if (i < e) atomicAdd(&deg[dst[i]], 1);
}

__global__ __launch_bounds__(SCAN_BLK) void k_part(const int* __restrict__ deg,
                                                   int* __restrict__ part) {
    __shared__ int s[SCAN_BLK];
    int i = blockIdx.x * SCAN_BLK + threadIdx.x;
    s[threadIdx.x] = (i < NN) ? deg[i] : 0;
    __syncthreads();
#pragma unroll
    for (int off = SCAN_BLK / 2; off > 0; off >>= 1) {
        if (threadIdx.x < off) s[threadIdx.x] += s[threadIdx.x + off];
        __syncthreads();
    }
    if (threadIdx.x == 0) part[blockIdx.x] = s[0];
}

__global__ __launch_bounds__(128) void k_scan_small(int* __restrict__ part) {
    __shared__ int s[128];
    int tid = threadIdx.x;
    int v = (tid < SCAN_NB) ? part[tid] : 0;
    s[tid] = v;
    __syncthreads();
#pragma unroll
    for (int off = 1; off < 128; off <<= 1) {
        int t = (tid >= off) ? s[tid - off] : 0;
        __syncthreads();
        s[tid] += t;
        __syncthreads();
    }
    if (tid < SCAN_NB) part[tid] = s[tid] - v;
}

__global__ __launch_bounds__(SCAN_BLK) void k_rows(const int* __restrict__ deg,
                                                   const int* __restrict__ part,
                                                   int* __restrict__ row_start,
                                                   int* __restrict__ cursor,
                                                   float* __restrict__ inv_deg) {
    __shared__ int s[SCAN_BLK];
    int i = blockIdx.x * SCAN_BLK + threadIdx.x;
    int d = (i < NN) ? deg[i] : 0;
    s[threadIdx.x] = d;
    __syncthreads();
#pragma unroll
    for (int off = 1; off < SCAN_BLK; off <<= 1) {
        int t = (threadIdx.x >= off) ? s[threadIdx.x - off] : 0;
        __syncthreads();
        s[threadIdx.x] += t;
        __syncthreads();
    }
    int excl = s[threadIdx.x] - d + part[blockIdx.x];
    if (i < NN) {
        row_start[i] = excl;
        cursor[i] = excl;
        inv_deg[i] = 1.0f / (float)(d > 1 ? d : 1);
        if (i == NN - 1) row_start[NN] = excl + d;
    }
}

__global__ void k_fill(const int* __restrict__ src, const int* __restrict__ dst,
                       int* __restrict__ cursor, int* __restrict__ col, int e) {
    int i = blockIdx.x * blockDim.x + threadIdx.x;
    if (i < e) {
        int pos = atomicAdd(&cursor[dst[i]], 1);
        col[pos] = src[i];
    }
}

// ---------------- conversions ----------------

__global__ void k_xcvt(const float* __restrict__ x, ushort* __restrict__ xb, int n2) {
    int i = blockIdx.x * blockDim.x + threadIdx.x;
    if (i < n2) {
        float2 v = *(const float2*)(x + (size_t)i * 2);
        uint pk = (uint)f2b(v.x) | ((uint)f2b(v.y) << 16);
        *(uint*)(xb + (size_t)i * 2) = pk;
    }
}

struct WArgs {
    const float* wl[6];
    const float* wr[6];
    ushort* wc[6];
};

__global__ void k_wcvt(WArgs a) {
    const int khs[6] = {64, 128, 128, 64, 128, 128};
    const int shs[6] = {7, 8, 8, 7, 8, 8};
    const int off[6] = {0, 16384, 49152, 65536, 81920, 114688};
    int idx = blockIdx.x * blockDim.x + threadIdx.x;
    if (idx >= 131072) return;
    int L = 0;
#pragma unroll
    for (int i = 1; i < 6; ++i) if (idx >= off[i]) L = i;
    int j = idx - off[L];
    int KH = khs[L];
    int n = j >> shs[L];
    int kk = j & ((1 << shs[L]) - 1);
    float v = (kk < KH) ? a.wl[L][n * KH + kk] : a.wr[L][n * KH + kk - KH];
    a.wc[L][j] = f2b(v);
}

// ---------------- fused SAGE layer: CSR gather -> LDS, then MFMA GEMM + epilogue ----
// block = 256 threads (4 waves), 64 nodes per block.
// A = [agg | h_self] (M x 2KH). agg computed in-block into LDS; h_self streamed.
// DUAL: one gather, two towers' GEMMs (layer 0, shared agg of x).

struct SArgs {
    const ushort *hm, *hv;          // gather + self source per tower
    const int *row_start, *col;
    const float *inv_deg;
    const ushort *Wm, *Wv;
    const float *blm, *blv, *gm, *gv, *bbm, *bbv;
    void *outm, *outv;
};

template <int KH, int NOUT, bool DO_LN, bool DUAL>
__global__ __launch_bounds__(256) void k_sage(SArgs a) {
    constexpr int NT = NOUT / 16;
    constexpr int NK = (2 * KH) / 32;
    constexpr int TW = DUAL ? 2 : 1;
    constexpr int PAD = KH + 8;      // +16B row pad: conflict-free ds_read_b128
    __shared__ ushort aggS[64][PAD];

    int tow = DUAL ? 0 : blockIdx.y;
    const ushort* h = (DUAL || tow == 0) ? a.hm : a.hv;
    int lane = threadIdx.x & 63;
    int wid = threadIdx.x >> 6;
    int n0 = blockIdx.x * 64;

    // ---- gather phase: wave w computes agg rows w*16 .. w*16+15 ----
    for (int i = 0; i < 16; ++i) {
        int row = wid * 16 + i;
        int node = n0 + row;
        if (node < NN) {
            int s = a.row_start[node], e = a.row_start[node + 1];
            float sc = a.inv_deg[node];
            if (KH == 128) {
                float a0 = 0.f, a1 = 0.f;
                int p = s;
                for (; p + 3 < e; p += 4) {
                    int c0 = a.col[p], c1 = a.col[p + 1], c2 = a.col[p + 2], c3 = a.col[p + 3];
                    uint u0 = *(const uint*)(h + (size_t)c0 * 128 + lane * 2);
                    uint u1 = *(const uint*)(h + (size_t)c1 * 128 + lane * 2);
                    uint u2 = *(const uint*)(h + (size_t)c2 * 128 + lane * 2);
                    uint u3 = *(const uint*)(h + (size_t)c3 * 128 + lane * 2);
                    a0 += blo(u0) + blo(u1) + blo(u2) + blo(u3);
                    a1 += bhi(u0) + bhi(u1) + bhi(u2) + bhi(u3);
                }
                for (; p < e; ++p) {
                    uint u = *(const uint*)(h + (size_t)a.col[p] * 128 + lane * 2);
                    a0 += blo(u); a1 += bhi(u);
                }
                uint pk = (uint)f2b(a0 * sc) | ((uint)f2b(a1 * sc) << 16);
                *(uint*)&aggS[row][lane * 2] = pk;
            } else {
                float a0 = 0.f;
                int p = s;
                for (; p + 3 < e; p += 4) {
                    int c0 = a.col[p], c1 = a.col[p + 1], c2 = a.col[p + 2], c3 = a.col[p + 3];
                    a0 += __builtin_bit_cast(float, (uint)h[(size_t)c0 * 64 + lane] << 16)
                        + __builtin_bit_cast(float, (uint)h[(size_t)c1 * 64 + lane] << 16)
                        + __builtin_bit_cast(float, (uint)h[(size_t)c2 * 64 + lane] << 16)
                        + __builtin_bit_cast(float, (uint)h[(size_t)c3 * 64 + lane] << 16);
                }
                for (; p < e; ++p)
                    a0 += __builtin_bit_cast(float, (uint)h[(size_t)a.col[p] * 64 + lane] << 16);
                aggS[row][lane] = f2b(a0 * sc);
            }
        } else {
            if (KH == 128) *(uint*)&aggS[row][lane * 2] = 0u;
            else aggS[row][lane] = (ushort)0;
        }
    }
    __syncthreads();

    // ---- GEMM phase ----
    int r15 = lane & 15;
    int kseg = lane >> 4;
    int m0 = n0 + wid * 16;
    size_t arow = (size_t)(m0 + r15);
    int lrow = wid * 16 + r15;
    const ushort* W0 = (DUAL || tow == 0) ? a.Wm : a.Wv;

    f32x4 acc[TW][NT];
#pragma unroll
    for (int tt = 0; tt < TW; ++tt)
#pragma unroll
        for (int nt = 0; nt < NT; ++nt) acc[tt][nt] = (f32x4){0.f, 0.f, 0.f, 0.f};

#pragma unroll
    for (int ks = 0; ks < NK; ++ks) {
        int kc = ks * 32 + kseg * 8;
        short8 af;
        if (ks < KH / 32) {
            af = *(const short8*)&aggS[lrow][kc];
        } else {
            af = *(const short8*)(h + arow * KH + (kc - KH));
        }
#pragma unroll
        for (int nt = 0; nt < NT; ++nt) {
            short8 b0 = *(const short8*)(W0 + (size_t)(nt * 16 + r15) * (2 * KH) + kc);
            acc[0][nt] = __builtin_amdgcn_mfma_f32_16x16x32_bf16(af, b0, acc[0][nt], 0, 0, 0);
            if (DUAL) {
                short8 b1 = *(const short8*)(a.Wv + (size_t)(nt * 16 + r15) * (2 * KH) + kc);
                acc[1][nt] = __builtin_amdgcn_mfma_f32_16x16x32_bf16(af, b1, acc[1][nt], 0, 0, 0);
            }
        }
    }

    // ---- epilogue per tower ----
#pragma unroll
    for (int tt = 0; tt < TW; ++tt) {
        int t = DUAL ? tt : tow;
        const float* bl = t ? a.blv : a.blm;
#pragma unroll
        for (int nt = 0; nt < NT; ++nt) {
            float bb = bl[nt * 16 + r15];
#pragma unroll
            for (int r = 0; r < 4; ++r) acc[tt][nt][r] += bb;
        }
        if (DO_LN) {
            const float* g = t ? a.gv : a.gm;
            const float* b = t ? a.bbv : a.bbm;
            float s[4] = {0, 0, 0, 0}, q[4] = {0, 0, 0, 0};
#pragma unroll
            for (int nt = 0; nt < NT; ++nt)
#pragma unroll
                for (int r = 0; r < 4; ++r) { float v = acc[tt][nt][r]; s[r] += v; q[r] += v * v; }
#pragma unroll
            for (int off = 1; off < 16; off <<= 1)
#pragma unroll
                for (int r = 0; r < 4; ++r) { s[r] += __shfl_xor(s[r], off); q[r] += __shfl_xor(q[r], off); }
            float mean[4], rstd[4];
#pragma unroll
            for (int r = 0; r < 4; ++r) {
                mean[r] = s[r] * (1.0f / NOUT);
                float var = q[r] * (1.0f / NOUT) - mean[r] * mean[r];
                rstd[r] = rsqrtf(var + 1e-5f);
            }
            ushort* out = (ushort*)(t ? a.outv : a.outm);
#pragma unroll
            for (int nt = 0; nt < NT; ++nt) {
                int n = nt * 16 + r15;
                float gg = g[n], bb = b[n];
#pragma unroll
                for (int r = 0; r < 4; ++r) {
                    int row = m0 + kseg * 4 + r;
                    if (row < NN) {
                        float y = fmaxf((acc[tt][nt][r] - mean[r]) * rstd[r] * gg + bb, 0.0f);
                        out[(size_t)row * NOUT + n] = f2b(y);
                    }
                }
            }
        } else {
            float* out = (float*)(t ? a.outv : a.outm);
#pragma unroll
            for (int nt = 0; nt < NT; ++nt) {
                int n = nt * 16 + r15;
#pragma unroll
                for (int r = 0; r < 4; ++r) {
                    int row = m0 + kseg * 4 + r;
                    if (row < NN) out[(size_t)row * NOUT + n] = acc[tt][nt][r];
                }
            }
        }
    }
}

// ---------------- launch ----------------

extern "C" void kernel_launch(void* const* d_in, const int* in_sizes, int n_in,
                              void* d_out, int out_size, void* d_ws, size_t ws_size,
                              hipStream_t stream) {
    const float* x = (const float*)d_in[0];
    const int* ei = (const int*)d_in[1];
    const int* esrc = ei;
    const int* edst = ei + NE;

    const float* mWl0 = (const float*)d_in[2];
    const float* mbl0 = (const float*)d_in[3];
    const float* mWr0 = (const float*)d_in[4];
    const float* mg0  = (const float*)d_in[5];
    const float* mb0  = (const float*)d_in[6];
    const float* mWl1 = (const float*)d_in[7];
    const float* mbl1 = (const float*)d_in[8];
    const float* mWr1 = (const float*)d_in[9];
    const float* mg1  = (const float*)d_in[10];
    const float* mb1  = (const float*)d_in[11];
    const float* mWl2 = (const float*)d_in[12];
    const float* mbl2 = (const float*)d_in[13];
    const float* mWr2 = (const float*)d_in[14];
    const float* vWl0 = (const float*)d_in[15];
    const float* vbl0 = (const float*)d_in[16];
    const float* vWr0 = (const float*)d_in[17];
    const float* vg0  = (const float*)d_in[18];
    const float* vb0  = (const float*)d_in[19];
    const float* vWl1 = (const float*)d_in[20];
    const float* vbl1 = (const float*)d_in[21];
    const float* vWr1 = (const float*)d_in[22];
    const float* vg1  = (const float*)d_in[23];
    const float* vb1  = (const float*)d_in[24];
    const float* vWl2 = (const float*)d_in[25];
    const float* vbl2 = (const float*)d_in[26];
    const float* vWr2 = (const float*)d_in[27];

    char* p = (char*)d_ws;
    auto alloc = [&](size_t bytes) {
        void* r = (void*)p;
        p += (bytes + 255) & ~(size_t)255;
        return r;
    };
    int* deg       = (int*)alloc((size_t)NN * 4);
    int* part      = (int*)alloc((size_t)SCAN_NB * 4);
    int* row_start = (int*)alloc((size_t)(NN + 1) * 4);
    int* cursor    = (int*)alloc((size_t)NN * 4);
    int* col       = (int*)alloc((size_t)NE * 4);
    float* inv_deg = (float*)alloc((size_t)NN * 4);
    ushort* x_bf   = (ushort*)alloc((size_t)MPAD * 64 * 2);
    ushort* h1m    = (ushort*)alloc((size_t)MPAD * 128 * 2);
    ushort* h1v    = (ushort*)alloc((size_t)MPAD * 128 * 2);
    ushort* h2m    = (ushort*)alloc((size_t)MPAD * 128 * 2);
    ushort* h2v    = (ushort*)alloc((size_t)MPAD * 128 * 2);
    ushort* wc0    = (ushort*)alloc((size_t)128 * 128 * 2);
    ushort* wc1    = (ushort*)alloc((size_t)128 * 256 * 2);
    ushort* wc2    = (ushort*)alloc((size_t)64 * 256 * 2);
    ushort* wc3    = (ushort*)alloc((size_t)128 * 128 * 2);
    ushort* wc4    = (ushort*)alloc((size_t)128 * 256 * 2);
    ushort* wc5    = (ushort*)alloc((size_t)64 * 256 * 2);

    float* out_mu = (float*)d_out;
    float* out_lv = (float*)d_out + (size_t)NN * 64;

    // CSR build (parallel 3-phase scan)
    hipMemsetAsync(deg, 0, (size_t)NN * 4, stream);
    k_deg<<<(NE + 255) / 256, 256, 0, stream>>>(edst, deg, NE);
    k_part<<<SCAN_NB, SCAN_BLK, 0, stream>>>(deg, part);
    k_scan_small<<<1, 128, 0, stream>>>(part);
    k_rows<<<SCAN_NB, SCAN_BLK, 0, stream>>>(deg, part, row_start, cursor, inv_deg);
    k_fill<<<(NE + 255) / 256, 256, 0, stream>>>(esrc, edst, cursor, col, NE);

    // conversions
    k_xcvt<<<(NN * 64 / 2 + 255) / 256, 256, 0, stream>>>(x, x_bf, NN * 64 / 2);
    WArgs wa;
    wa.wl[0] = mWl0; wa.wr[0] = mWr0; wa.wc[0] = wc0;
    wa.wl[1] = mWl1; wa.wr[1] = mWr1; wa.wc[1] = wc1;
    wa.wl[2] = mWl2; wa.wr[2] = mWr2; wa.wc[2] = wc2;
    wa.wl[3] = vWl0; wa.wr[3] = vWr0; wa.wc[3] = wc3;
    wa.wl[4] = vWl1; wa.wr[4] = vWr1; wa.wc[4] = wc4;
    wa.wl[5] = vWl2; wa.wr[5] = vWr2; wa.wc[5] = wc5;
    k_wcvt<<<512, 256, 0, stream>>>(wa);

    // layer 0: one gather of x, both towers (DUAL)
    {
        SArgs sa = {x_bf, x_bf, row_start, col, inv_deg, wc0, wc3,
                    mbl0, vbl0, mg0, vg0, mb0, vb0, h1m, h1v};
        k_sage<64, 128, true, true><<<dim3(782, 1), 256, 0, stream>>>(sa);
    }
    // layer 1
    {
        SArgs sa = {h1m, h1v, row_start, col, inv_deg, wc1, wc4,
                    mbl1, vbl1, mg1, vg1, mb1, vb1, h2m, h2v};
        k_sage<128, 128, true, false><<<dim3(782, 2), 256, 0, stream>>>(sa);
    }
    // layer 2 (final, fp32 out, no LN)
    {
        SArgs sa = {h2m, h2v, row_start, col, inv_deg, wc2, wc5,
                    mbl2, vbl2, nullptr, nullptr, nullptr, nullptr, out_mu, out_lv};
        k_sage<128, 64, false, false><<<dim3(782, 2), 256, 0, stream>>>(sa);
    }
}

// Round 5
// 493.403 us; speedup vs baseline: 1.4209x; 1.4209x over previous
//
#include <hip/hip_runtime.h>

#define NN 50000
#define NE 800000
#define MPAD 50048   // 782 * 64
#define SCAN_BLK 512
#define SCAN_NB 98   // ceil(NN/512)

typedef __attribute__((ext_vector_type(8))) short short8;
typedef __attribute__((ext_vector_type(4))) float f32x4;

__device__ __forceinline__ ushort f2b(float f) {
    uint u = __builtin_bit_cast(uint, f);
    uint r = (u + 0x7fffu + ((u >> 16) & 1u)) >> 16;
    return (ushort)r;
}
__device__ __forceinline__ uint pk2(float a, float b) {
    return (uint)f2b(a) | ((uint)f2b(b) << 16);
}
__device__ __forceinline__ float blo(uint u) { return __builtin_bit_cast(float, u << 16); }
__device__ __forceinline__ float bhi(uint u) { return __builtin_bit_cast(float, u & 0xffff0000u); }

// ---------------- CSR build ----------------

__global__ void k_deg(const int* __restrict__ dst, int* __restrict__ deg, int e) {
    int i = blockIdx.x * blockDim.x + threadIdx.x;
    if (i < e) atomicAdd(&deg[dst[i]], 1);
}

__global__ __launch_bounds__(SCAN_BLK) void k_part(const int* __restrict__ deg,
                                                   int* __restrict__ part) {
    __shared__ int s[SCAN_BLK];
    int i = blockIdx.x * SCAN_BLK + threadIdx.x;
    s[threadIdx.x] = (i < NN) ? deg[i] : 0;
    __syncthreads();
#pragma unroll
    for (int off = SCAN_BLK / 2; off > 0; off >>= 1) {
        if (threadIdx.x < off) s[threadIdx.x] += s[threadIdx.x + off];
        __syncthreads();
    }
    if (threadIdx.x == 0) part[blockIdx.x] = s[0];
}

__global__ __launch_bounds__(128) void k_scan_small(int* __restrict__ part) {
    __shared__ int s[128];
    int tid = threadIdx.x;
    int v = (tid < SCAN_NB) ? part[tid] : 0;
    s[tid] = v;
    __syncthreads();
#pragma unroll
    for (int off = 1; off < 128; off <<= 1) {
        int t = (tid >= off) ? s[tid - off] : 0;
        __syncthreads();
        s[tid] += t;
        __syncthreads();
    }
    if (tid < SCAN_NB) part[tid] = s[tid] - v;
}

__global__ __launch_bounds__(SCAN_BLK) void k_rows(const int* __restrict__ deg,
                                                   const int* __restrict__ part,
                                                   int* __restrict__ row_start,
                                                   int* __restrict__ cursor,
                                                   float* __restrict__ inv_deg) {
    __shared__ int s[SCAN_BLK];
    int i = blockIdx.x * SCAN_BLK + threadIdx.x;
    int d = (i < NN) ? deg[i] : 0;
    s[threadIdx.x] = d;
    __syncthreads();
#pragma unroll
    for (int off = 1; off < SCAN_BLK; off <<= 1) {
        int t = (threadIdx.x >= off) ? s[threadIdx.x - off] : 0;
        __syncthreads();
        s[threadIdx.x] += t;
        __syncthreads();
    }
    int excl = s[threadIdx.x] - d + part[blockIdx.x];
    if (i < NN) {
        row_start[i] = excl;
        cursor[i] = excl;
        inv_deg[i] = 1.0f / (float)(d > 1 ? d : 1);
        if (i == NN - 1) row_start[NN] = excl + d;
    }
}

__global__ void k_fill(const int* __restrict__ src, const int* __restrict__ dst,
                       int* __restrict__ cursor, int* __restrict__ col, int e) {
    int i = blockIdx.x * blockDim.x + threadIdx.x;
    if (i < e) {
        int pos = atomicAdd(&cursor[dst[i]], 1);
        col[pos] = src[i];
    }
}

// ---------------- conversions ----------------

__global__ void k_xcvt(const float* __restrict__ x, ushort* __restrict__ xb, int n2) {
    int i = blockIdx.x * blockDim.x + threadIdx.x;
    if (i < n2) {
        float2 v = *(const float2*)(x + (size_t)i * 2);
        *(uint*)(xb + (size_t)i * 2) = pk2(v.x, v.y);
    }
}

struct WArgs {
    const float* wl[6];
    const float* wr[6];
    ushort* wc[6];
};

__global__ void k_wcvt(WArgs a) {
    const int khs[6] = {64, 128, 128, 64, 128, 128};
    const int shs[6] = {7, 8, 8, 7, 8, 8};
    const int off[6] = {0, 16384, 49152, 65536, 81920, 114688};
    int idx = blockIdx.x * blockDim.x + threadIdx.x;
    if (idx >= 131072) return;
    int L = 0;
#pragma unroll
    for (int i = 1; i < 6; ++i) if (idx >= off[i]) L = i;
    int j = idx - off[L];
    int KH = khs[L];
    int n = j >> shs[L];
    int kk = j & ((1 << shs[L]) - 1);
    float v = (kk < KH) ? a.wl[L][n * KH + kk] : a.wr[L][n * KH + kk - KH];
    a.wc[L][j] = f2b(v);
}

// ---------------- mean aggregation: 16-lane group per node, dwordx4 rows ----------------

__device__ __forceinline__ void acc8(float* a, uint4 u) {
    a[0] += blo(u.x); a[1] += bhi(u.x);
    a[2] += blo(u.y); a[3] += bhi(u.y);
    a[4] += blo(u.z); a[5] += bhi(u.z);
    a[6] += blo(u.w); a[7] += bhi(u.w);
}
__device__ __forceinline__ void acc4(float* a, uint2 u) {
    a[0] += blo(u.x); a[1] += bhi(u.x);
    a[2] += blo(u.y); a[3] += bhi(u.y);
}

template <int D>
__global__ __launch_bounds__(256) void k_agg(
    const ushort* __restrict__ h,
    const int* __restrict__ row_start, const int* __restrict__ col,
    const float* __restrict__ inv_deg, ushort* __restrict__ o) {
    int node = (blockIdx.x * 256 + threadIdx.x) >> 4;  // 16-lane group per node
    int li = threadIdx.x & 15;
    if (node >= NN) return;
    int s = row_start[node], e = row_start[node + 1];
    float sc = inv_deg[node];
    if (D == 128) {
        const ushort* hb = h + (size_t)li * 8;
        float a[8] = {0, 0, 0, 0, 0, 0, 0, 0};
        int p = s;
        for (; p + 3 < e; p += 4) {
            int c0 = col[p], c1 = col[p + 1], c2 = col[p + 2], c3 = col[p + 3];
            uint4 u0 = *(const uint4*)(hb + (size_t)c0 * 128);
            uint4 u1 = *(const uint4*)(hb + (size_t)c1 * 128);
            uint4 u2 = *(const uint4*)(hb + (size_t)c2 * 128);
            uint4 u3 = *(const uint4*)(hb + (size_t)c3 * 128);
            acc8(a, u0); acc8(a, u1); acc8(a, u2); acc8(a, u3);
        }
        for (; p < e; ++p) {
            uint4 u = *(const uint4*)(hb + (size_t)col[p] * 128);
            acc8(a, u);
        }
        uint4 r;
        r.x = pk2(a[0] * sc, a[1] * sc);
        r.y = pk2(a[2] * sc, a[3] * sc);
        r.z = pk2(a[4] * sc, a[5] * sc);
        r.w = pk2(a[6] * sc, a[7] * sc);
        *(uint4*)(o + (size_t)node * 128 + li * 8) = r;
    } else {
        const ushort* hb = h + (size_t)li * 4;
        float a[4] = {0, 0, 0, 0};
        int p = s;
        for (; p + 3 < e; p += 4) {
            int c0 = col[p], c1 = col[p + 1], c2 = col[p + 2], c3 = col[p + 3];
            uint2 u0 = *(const uint2*)(hb + (size_t)c0 * 64);
            uint2 u1 = *(const uint2*)(hb + (size_t)c1 * 64);
            uint2 u2 = *(const uint2*)(hb + (size_t)c2 * 64);
            uint2 u3 = *(const uint2*)(hb + (size_t)c3 * 64);
            acc4(a, u0); acc4(a, u1); acc4(a, u2); acc4(a, u3);
        }
        for (; p < e; ++p) {
            uint2 u = *(const uint2*)(hb + (size_t)col[p] * 64);
            acc4(a, u);
        }
        uint2 r;
        r.x = pk2(a[0] * sc, a[1] * sc);
        r.y = pk2(a[2] * sc, a[3] * sc);
        *(uint2*)(o + (size_t)node * 64 + li * 4) = r;
    }
}

// ---------------- fused MFMA GEMM (+bias [+LN+ReLU]) ----------------
// C[M x NOUT] = [agg | h] (M x 2KH, bf16) * Wcat^T. Per-wave 16 rows.
// __launch_bounds__(256,4): 128-VGPR budget so all NK A-frags preload.

struct GArgs {
    const ushort *A1m, *A1v, *A2m, *A2v, *Wm, *Wv;
    const float *blm, *blv, *gm, *gv, *bbm, *bbv;
    void *outm, *outv;
};

template <int KH, int NOUT, bool DO_LN>
__global__ __launch_bounds__(256, 4) void k_gemm(GArgs a) {
    constexpr int NT = NOUT / 16;
    constexpr int NK = (2 * KH) / 32;
    int tow = blockIdx.y;
    const ushort* A1 = tow ? a.A1v : a.A1m;
    const ushort* A2 = tow ? a.A2v : a.A2m;
    const ushort* W  = tow ? a.Wv  : a.Wm;
    const float* bl  = tow ? a.blv : a.blm;
    int lane = threadIdx.x & 63;
    int wid  = threadIdx.x >> 6;
    int m0 = blockIdx.x * 64 + wid * 16;
    int r15 = lane & 15;
    int kseg = lane >> 4;
    size_t arow = (size_t)(m0 + r15);

    // preload ALL A fragments (issues every global A-load up front)
    short8 afr[NK];
#pragma unroll
    for (int ks = 0; ks < NK; ++ks) {
        int kc = ks * 32 + kseg * 8;
        afr[ks] = (ks < KH / 32) ? *(const short8*)(A1 + arow * KH + kc)
                                 : *(const short8*)(A2 + arow * KH + (kc - KH));
    }

    f32x4 acc[NT];
#pragma unroll
    for (int nt = 0; nt < NT; ++nt) acc[nt] = (f32x4){0.f, 0.f, 0.f, 0.f};

#pragma unroll
    for (int ks = 0; ks < NK; ++ks) {
        int kc = ks * 32 + kseg * 8;
#pragma unroll
        for (int nt = 0; nt < NT; ++nt) {
            short8 bfr = *(const short8*)(W + (size_t)(nt * 16 + r15) * (2 * KH) + kc);
            acc[nt] = __builtin_amdgcn_mfma_f32_16x16x32_bf16(afr[ks], bfr, acc[nt], 0, 0, 0);
        }
    }

#pragma unroll
    for (int nt = 0; nt < NT; ++nt) {
        float bb = bl[nt * 16 + r15];
#pragma unroll
        for (int r = 0; r < 4; ++r) acc[nt][r] += bb;
    }

    if (DO_LN) {
        const float* g = tow ? a.gv : a.gm;
        const float* b = tow ? a.bbv : a.bbm;
        float s[4] = {0, 0, 0, 0}, q[4] = {0, 0, 0, 0};
#pragma unroll
        for (int nt = 0; nt < NT; ++nt)
#pragma unroll
            for (int r = 0; r < 4; ++r) { float v = acc[nt][r]; s[r] += v; q[r] += v * v; }
#pragma unroll
        for (int off = 1; off < 16; off <<= 1)
#pragma unroll
            for (int r = 0; r < 4; ++r) { s[r] += __shfl_xor(s[r], off); q[r] += __shfl_xor(q[r], off); }
        float mean[4], rstd[4];
#pragma unroll
        for (int r = 0; r < 4; ++r) {
            mean[r] = s[r] * (1.0f / NOUT);
            float var = q[r] * (1.0f / NOUT) - mean[r] * mean[r];
            rstd[r] = rsqrtf(var + 1e-5f);
        }
        ushort* out = (ushort*)(tow ? a.outv : a.outm);
#pragma unroll
        for (int nt = 0; nt < NT; ++nt) {
            int n = nt * 16 + r15;
            float gg = g[n], bb = b[n];
#pragma unroll
            for (int r = 0; r < 4; ++r) {
                int row = m0 + kseg * 4 + r;
                if (row < NN) {
                    float y = fmaxf((acc[nt][r] - mean[r]) * rstd[r] * gg + bb, 0.0f);
                    out[(size_t)row * NOUT + n] = f2b(y);
                }
            }
        }
    } else {
        float* out = (float*)(tow ? a.outv : a.outm);
#pragma unroll
        for (int nt = 0; nt < NT; ++nt) {
            int n = nt * 16 + r15;
#pragma unroll
            for (int r = 0; r < 4; ++r) {
                int row = m0 + kseg * 4 + r;
                if (row < NN) out[(size_t)row * NOUT + n] = acc[nt][r];
            }
        }
    }
}

// ---------------- launch ----------------

extern "C" void kernel_launch(void* const* d_in, const int* in_sizes, int n_in,
                              void* d_out, int out_size, void* d_ws, size_t ws_size,
                              hipStream_t stream) {
    const float* x = (const float*)d_in[0];
    const int* ei = (const int*)d_in[1];
    const int* esrc = ei;
    const int* edst = ei + NE;

    const float* mWl0 = (const float*)d_in[2];
    const float* mbl0 = (const float*)d_in[3];
    const float* mWr0 = (const float*)d_in[4];
    const float* mg0  = (const float*)d_in[5];
    const float* mb0  = (const float*)d_in[6];
    const float* mWl1 = (const float*)d_in[7];
    const float* mbl1 = (const float*)d_in[8];
    const float* mWr1 = (const float*)d_in[9];
    const float* mg1  = (const float*)d_in[10];
    const float* mb1  = (const float*)d_in[11];
    const float* mWl2 = (const float*)d_in[12];
    const float* mbl2 = (const float*)d_in[13];
    const float* mWr2 = (const float*)d_in[14];
    const float* vWl0 = (const float*)d_in[15];
    const float* vbl0 = (const float*)d_in[16];
    const float* vWr0 = (const float*)d_in[17];
    const float* vg0  = (const float*)d_in[18];
    const float* vb0  = (const float*)d_in[19];
    const float* vWl1 = (const float*)d_in[20];
    const float* vbl1 = (const float*)d_in[21];
    const float* vWr1 = (const float*)d_in[22];
    const float* vg1  = (const float*)d_in[23];
    const float* vb1  = (const float*)d_in[24];
    const float* vWl2 = (const float*)d_in[25];
    const float* vbl2 = (const float*)d_in[26];
    const float* vWr2 = (const float*)d_in[27];

    char* p = (char*)d_ws;
    auto alloc = [&](size_t bytes) {
        void* r = (void*)p;
        p += (bytes + 255) & ~(size_t)255;
        return r;
    };
    int* deg       = (int*)alloc((size_t)NN * 4);
    int* part      = (int*)alloc((size_t)SCAN_NB * 4);
    int* row_start = (int*)alloc((size_t)(NN + 1) * 4);
    int* cursor    = (int*)alloc((size_t)NN * 4);
    int* col       = (int*)alloc((size_t)NE * 4);
    float* inv_deg = (float*)alloc((size_t)NN * 4);
    ushort* x_bf   = (ushort*)alloc((size_t)MPAD * 64 * 2);
    ushort* agg0   = (ushort*)alloc((size_t)MPAD * 64 * 2);
    ushort* h1m    = (ushort*)alloc((size_t)MPAD * 128 * 2);
    ushort* h1v    = (ushort*)alloc((size_t)MPAD * 128 * 2);
    ushort* h2m    = (ushort*)alloc((size_t)MPAD * 128 * 2);
    ushort* h2v    = (ushort*)alloc((size_t)MPAD * 128 * 2);
    ushort* aggm   = (ushort*)alloc((size_t)MPAD * 128 * 2);
    ushort* aggv   = (ushort*)alloc((size_t)MPAD * 128 * 2);
    ushort* wc0    = (ushort*)alloc((size_t)128 * 128 * 2);
    ushort* wc1    = (ushort*)alloc((size_t)128 * 256 * 2);
    ushort* wc2    = (ushort*)alloc((size_t)64 * 256 * 2);
    ushort* wc3    = (ushort*)alloc((size_t)128 * 128 * 2);
    ushort* wc4    = (ushort*)alloc((size_t)128 * 256 * 2);
    ushort* wc5    = (ushort*)alloc((size_t)64 * 256 * 2);

    float* out_mu = (float*)d_out;
    float* out_lv = (float*)d_out + (size_t)NN * 64;

    // CSR build (parallel 3-phase scan)
    hipMemsetAsync(deg, 0, (size_t)NN * 4, stream);
    k_deg<<<(NE + 255) / 256, 256, 0, stream>>>(edst, deg, NE);
    k_part<<<SCAN_NB, SCAN_BLK, 0, stream>>>(deg, part);
    k_scan_small<<<1, 128, 0, stream>>>(part);
    k_rows<<<SCAN_NB, SCAN_BLK, 0, stream>>>(deg, part, row_start, cursor, inv_deg);
    k_fill<<<(NE + 255) / 256, 256, 0, stream>>>(esrc, edst, cursor, col, NE);

    // conversions
    k_xcvt<<<(NN * 64 / 2 + 255) / 256, 256, 0, stream>>>(x, x_bf, NN * 64 / 2);
    WArgs wa;
    wa.wl[0] = mWl0; wa.wr[0] = mWr0; wa.wc[0] = wc0;
    wa.wl[1] = mWl1; wa.wr[1] = mWr1; wa.wc[1] = wc1;
    wa.wl[2] = mWl2; wa.wr[2] = mWr2; wa.wc[2] = wc2;
    wa.wl[3] = vWl0; wa.wr[3] = vWr0; wa.wc[3] = wc3;
    wa.wl[4] = vWl1; wa.wr[4] = vWr1; wa.wc[4] = wc4;
    wa.wl[5] = vWl2; wa.wr[5] = vWr2; wa.wc[5] = wc5;
    k_wcvt<<<512, 256, 0, stream>>>(wa);

    const int gA = (NN * 16 + 255) / 256;  // 16-lane group per node
    const dim3 gG(782, 2);

    // layer 0: shared agg of x (one gather, both towers' GEMMs read it)
    k_agg<64><<<gA, 256, 0, stream>>>(x_bf, row_start, col, inv_deg, agg0);
    {
        GArgs ga = {agg0, agg0, x_bf, x_bf, wc0, wc3,
                    mbl0, vbl0, mg0, vg0, mb0, vb0, h1m, h1v};
        k_gemm<64, 128, true><<<gG, 256, 0, stream>>>(ga);
    }
    // layer 1 (towers as separate agg dispatches for L2 locality)
    k_agg<128><<<gA, 256, 0, stream>>>(h1m, row_start, col, inv_deg, aggm);
    k_agg<128><<<gA, 256, 0, stream>>>(h1v, row_start, col, inv_deg, aggv);
    {
        GArgs ga = {aggm, aggv, h1m, h1v, wc1, wc4,
                    mbl1, vbl1, mg1, vg1, mb1, vb1, h2m, h2v};
        k_gemm<128, 128, true><<<gG, 256, 0, stream>>>(ga);
    }
    // layer 2 (final, fp32 out, no LN)
    k_agg<128><<<gA, 256, 0, stream>>>(h2m, row_start, col, inv_deg, aggm);
    k_agg<128><<<gA, 256, 0, stream>>>(h2v, row_start, col, inv_deg, aggv);
    {
        GArgs ga = {aggm, aggv, h2m, h2v, wc2, wc5,
                    mbl2, vbl2, nullptr, nullptr, nullptr, nullptr, out_mu, out_lv};
        k_gemm<128, 64, false><<<gG, 256, 0, stream>>>(ga);
    }
}

// Round 6
// 437.611 us; speedup vs baseline: 1.6020x; 1.1275x over previous
//
#include <hip/hip_runtime.h>

#define NN 50000
#define NE 800000
#define MPAD 50048   // 391 * 128
#define SCAN_BLK 512
#define SCAN_NB 98   // ceil(NN/512)

typedef __attribute__((ext_vector_type(8))) short short8;
typedef __attribute__((ext_vector_type(4))) float f32x4;

__device__ __forceinline__ ushort f2b(float f) {
    uint u = __builtin_bit_cast(uint, f);
    uint r = (u + 0x7fffu + ((u >> 16) & 1u)) >> 16;
    return (ushort)r;
}
__device__ __forceinline__ uint pk2(float a, float b) {
    return (uint)f2b(a) | ((uint)f2b(b) << 16);
}
__device__ __forceinline__ float blo(uint u) { return __builtin_bit_cast(float, u << 16); }
__device__ __forceinline__ float bhi(uint u) { return __builtin_bit_cast(float, u & 0xffff0000u); }

// ---------------- CSR build ----------------

__global__ void k_deg(const int* __restrict__ dst, int* __restrict__ deg, int e) {
    int i = blockIdx.x * blockDim.x + threadIdx.x;
    if (i < e) atomicAdd(&deg[dst[i]], 1);
}

__global__ __launch_bounds__(SCAN_BLK) void k_part(const int* __restrict__ deg,
                                                   int* __restrict__ part) {
    __shared__ int s[SCAN_BLK];
    int i = blockIdx.x * SCAN_BLK + threadIdx.x;
    s[threadIdx.x] = (i < NN) ? deg[i] : 0;
    __syncthreads();
#pragma unroll
    for (int off = SCAN_BLK / 2; off > 0; off >>= 1) {
        if (threadIdx.x < off) s[threadIdx.x] += s[threadIdx.x + off];
        __syncthreads();
    }
    if (threadIdx.x == 0) part[blockIdx.x] = s[0];
}

__global__ __launch_bounds__(128) void k_scan_small(int* __restrict__ part) {
    __shared__ int s[128];
    int tid = threadIdx.x;
    int v = (tid < SCAN_NB) ? part[tid] : 0;
    s[tid] = v;
    __syncthreads();
#pragma unroll
    for (int off = 1; off < 128; off <<= 1) {
        int t = (tid >= off) ? s[tid - off] : 0;
        __syncthreads();
        s[tid] += t;
        __syncthreads();
    }
    if (tid < SCAN_NB) part[tid] = s[tid] - v;
}

__global__ __launch_bounds__(SCAN_BLK) void k_rows(const int* __restrict__ deg,
                                                   const int* __restrict__ part,
                                                   int* __restrict__ row_start,
                                                   int* __restrict__ cursor,
                                                   float* __restrict__ inv_deg) {
    __shared__ int s[SCAN_BLK];
    int i = blockIdx.x * SCAN_BLK + threadIdx.x;
    int d = (i < NN) ? deg[i] : 0;
    s[threadIdx.x] = d;
    __syncthreads();
#pragma unroll
    for (int off = 1; off < SCAN_BLK; off <<= 1) {
        int t = (threadIdx.x >= off) ? s[threadIdx.x - off] : 0;
        __syncthreads();
        s[threadIdx.x] += t;
        __syncthreads();
    }
    int excl = s[threadIdx.x] - d + part[blockIdx.x];
    if (i < NN) {
        row_start[i] = excl;
        cursor[i] = excl;
        inv_deg[i] = 1.0f / (float)(d > 1 ? d : 1);
        if (i == NN - 1) row_start[NN] = excl + d;
    }
}

__global__ void k_fill(const int* __restrict__ src, const int* __restrict__ dst,
                       int* __restrict__ cursor, int* __restrict__ col, int e) {
    int i = blockIdx.x * blockDim.x + threadIdx.x;
    if (i < e) {
        int pos = atomicAdd(&cursor[dst[i]], 1);
        col[pos] = src[i];
    }
}

// ---------------- conversions ----------------

__global__ void k_xcvt(const float* __restrict__ x, ushort* __restrict__ xb, int n2) {
    int i = blockIdx.x * blockDim.x + threadIdx.x;
    if (i < n2) {
        float2 v = *(const float2*)(x + (size_t)i * 2);
        *(uint*)(xb + (size_t)i * 2) = pk2(v.x, v.y);
    }
}

struct WArgs {
    const float* wl[6];
    const float* wr[6];
    ushort* wc[6];
};

// build Wcat = [Wl | Wr] in bf16, stored in MFMA FRAGMENT-STREAM order:
// elem (row n, col c) -> ((ks*NT + nt)*512) + lane*8 + j
// where ks=c>>5, kseg=(c>>3)&3, j=c&7, nt=n>>4, r15=n&15, lane=kseg*16+r15.
__global__ void k_wcvt(WArgs a) {
    const int khs[6] = {64, 128, 128, 64, 128, 128};
    const int nts[6] = {8, 8, 4, 8, 8, 4};
    const int shs[6] = {7, 8, 8, 7, 8, 8};   // log2(2*KH)
    const int off[6] = {0, 16384, 49152, 65536, 81920, 114688};
    int idx = blockIdx.x * blockDim.x + threadIdx.x;
    if (idx >= 131072) return;
    int L = 0;
#pragma unroll
    for (int i = 1; i < 6; ++i) if (idx >= off[i]) L = i;
    int j = idx - off[L];
    int KH = khs[L];
    int n = j >> shs[L];
    int c = j & ((1 << shs[L]) - 1);
    float v = (c < KH) ? a.wl[L][n * KH + c] : a.wr[L][n * KH + c - KH];
    int ks = c >> 5, kseg = (c >> 3) & 3, jj = c & 7;
    int nt = n >> 4, r15 = n & 15;
    int lane = (kseg << 4) | r15;
    int foff = ((ks * nts[L] + nt) << 9) + (lane << 3) + jj;
    a.wc[L][foff] = f2b(v);
}

// ---------------- mean aggregation: 16-lane group per node, dwordx4 rows ----------------

__device__ __forceinline__ void acc8(float* a, uint4 u) {
    a[0] += blo(u.x); a[1] += bhi(u.x);
    a[2] += blo(u.y); a[3] += bhi(u.y);
    a[4] += blo(u.z); a[5] += bhi(u.z);
    a[6] += blo(u.w); a[7] += bhi(u.w);
}
__device__ __forceinline__ void acc4(float* a, uint2 u) {
    a[0] += blo(u.x); a[1] += bhi(u.x);
    a[2] += blo(u.y); a[3] += bhi(u.y);
}

template <int D>
__global__ __launch_bounds__(256) void k_agg(
    const ushort* __restrict__ h,
    const int* __restrict__ row_start, const int* __restrict__ col,
    const float* __restrict__ inv_deg, ushort* __restrict__ o) {
    int node = (blockIdx.x * 256 + threadIdx.x) >> 4;  // 16-lane group per node
    int li = threadIdx.x & 15;
    if (node >= NN) return;
    int s = row_start[node], e = row_start[node + 1];
    float sc = inv_deg[node];
    if (D == 128) {
        const ushort* hb = h + (size_t)li * 8;
        float a[8] = {0, 0, 0, 0, 0, 0, 0, 0};
        int p = s;
        for (; p + 3 < e; p += 4) {
            int c0 = col[p], c1 = col[p + 1], c2 = col[p + 2], c3 = col[p + 3];
            uint4 u0 = *(const uint4*)(hb + (size_t)c0 * 128);
            uint4 u1 = *(const uint4*)(hb + (size_t)c1 * 128);
            uint4 u2 = *(const uint4*)(hb + (size_t)c2 * 128);
            uint4 u3 = *(const uint4*)(hb + (size_t)c3 * 128);
            acc8(a, u0); acc8(a, u1); acc8(a, u2); acc8(a, u3);
        }
        for (; p < e; ++p) {
            uint4 u = *(const uint4*)(hb + (size_t)col[p] * 128);
            acc8(a, u);
        }
        uint4 r;
        r.x = pk2(a[0] * sc, a[1] * sc);
        r.y = pk2(a[2] * sc, a[3] * sc);
        r.z = pk2(a[4] * sc, a[5] * sc);
        r.w = pk2(a[6] * sc, a[7] * sc);
        *(uint4*)(o + (size_t)node * 128 + li * 8) = r;
    } else {
        const ushort* hb = h + (size_t)li * 4;
        float a[4] = {0, 0, 0, 0};
        int p = s;
        for (; p + 3 < e; p += 4) {
            int c0 = col[p], c1 = col[p + 1], c2 = col[p + 2], c3 = col[p + 3];
            uint2 u0 = *(const uint2*)(hb + (size_t)c0 * 64);
            uint2 u1 = *(const uint2*)(hb + (size_t)c1 * 64);
            uint2 u2 = *(const uint2*)(hb + (size_t)c2 * 64);
            uint2 u3 = *(const uint2*)(hb + (size_t)c3 * 64);
            acc4(a, u0); acc4(a, u1); acc4(a, u2); acc4(a, u3);
        }
        for (; p < e; ++p) {
            uint2 u = *(const uint2*)(hb + (size_t)col[p] * 64);
            acc4(a, u);
        }
        uint2 r;
        r.x = pk2(a[0] * sc, a[1] * sc);
        r.y = pk2(a[2] * sc, a[3] * sc);
        *(uint2*)(o + (size_t)node * 64 + li * 4) = r;
    }
}

// ---------------- MFMA GEMM with LDS-resident fragment-ordered W ----------------
// Block: 256 threads (4 waves), BM=128 rows (each wave: 2 row-tiles of 16).
// W staged to LDS in fragment-stream order -> linear conflict-free ds_read_b128.
// DUAL (layer 0): both towers' W in LDS, one A-frag feeds 2 towers (grid.y=1).

struct GArgs {
    const ushort *A1m, *A1v, *A2m, *A2v, *Wm, *Wv;
    const float *blm, *blv, *gm, *gv, *bbm, *bbv;
    void *outm, *outv;
};

template <int KH, int NOUT, bool DO_LN, bool DUAL>
__global__ __launch_bounds__(256, 2) void k_gemm(GArgs a) {
    constexpr int NT = NOUT / 16;
    constexpr int NK = KH / 16;            // (2*KH)/32
    constexpr int TW = DUAL ? 2 : 1;
    constexpr int WCH = NOUT * KH * 4 / 16;  // uint4 chunks per tower (NOUT*2KH*2B/16)
    __shared__ uint4 wlds[TW * WCH];

    int tid = threadIdx.x;
    int lane = tid & 63, wid = tid >> 6;
    int tow = DUAL ? 0 : blockIdx.y;
    const ushort* A1 = tow ? a.A1v : a.A1m;
    const ushort* A2 = tow ? a.A2v : a.A2m;

    // stage W (fragment order, linear copy)
    {
        const uint4* w0 = (const uint4*)(tow ? a.Wv : a.Wm);
        for (int i = tid; i < WCH; i += 256) wlds[i] = w0[i];
        if (DUAL) {
            const uint4* w1 = (const uint4*)a.Wv;
            for (int i = tid; i < WCH; i += 256) wlds[WCH + i] = w1[i];
        }
    }

    int r15 = lane & 15, kseg = lane >> 4;
    int m0 = blockIdx.x * 128 + wid * 32;
    size_t ar0 = (size_t)(m0 + r15);
    size_t ar1 = (size_t)(m0 + 16 + r15);

    // preload all A fragments for both row-tiles (global, issued before sync)
    short8 af[2][NK];
#pragma unroll
    for (int ks = 0; ks < NK; ++ks) {
        int kc = ks * 32 + kseg * 8;
        af[0][ks] = (kc < KH) ? *(const short8*)(A1 + ar0 * KH + kc)
                              : *(const short8*)(A2 + ar0 * KH + (kc - KH));
        af[1][ks] = (kc < KH) ? *(const short8*)(A1 + ar1 * KH + kc)
                              : *(const short8*)(A2 + ar1 * KH + (kc - KH));
    }
    __syncthreads();

    f32x4 acc[TW][2][NT];
#pragma unroll
    for (int tt = 0; tt < TW; ++tt)
#pragma unroll
        for (int t = 0; t < 2; ++t)
#pragma unroll
            for (int nt = 0; nt < NT; ++nt) acc[tt][t][nt] = (f32x4){0.f, 0.f, 0.f, 0.f};

#pragma unroll
    for (int ks = 0; ks < NK; ++ks) {
#pragma unroll
        for (int nt = 0; nt < NT; ++nt) {
#pragma unroll
            for (int tt = 0; tt < TW; ++tt) {
                short8 w = *(const short8*)&wlds[tt * WCH + (ks * NT + nt) * 64 + lane];
                acc[tt][0][nt] = __builtin_amdgcn_mfma_f32_16x16x32_bf16(af[0][ks], w, acc[tt][0][nt], 0, 0, 0);
                acc[tt][1][nt] = __builtin_amdgcn_mfma_f32_16x16x32_bf16(af[1][ks], w, acc[tt][1][nt], 0, 0, 0);
            }
        }
    }

    // epilogue
#pragma unroll
    for (int tt = 0; tt < TW; ++tt) {
        int tsel = DUAL ? tt : tow;
        const float* bl = tsel ? a.blv : a.blm;
#pragma unroll
        for (int nt = 0; nt < NT; ++nt) {
            float bb = bl[nt * 16 + r15];
#pragma unroll
            for (int t = 0; t < 2; ++t)
#pragma unroll
                for (int r = 0; r < 4; ++r) acc[tt][t][nt][r] += bb;
        }
        if (DO_LN) {
            const float* g = tsel ? a.gv : a.gm;
            const float* b = tsel ? a.bbv : a.bbm;
#pragma unroll
            for (int t = 0; t < 2; ++t) {
                float s[4] = {0, 0, 0, 0}, q[4] = {0, 0, 0, 0};
#pragma unroll
                for (int nt = 0; nt < NT; ++nt)
#pragma unroll
                    for (int r = 0; r < 4; ++r) { float v = acc[tt][t][nt][r]; s[r] += v; q[r] += v * v; }
#pragma unroll
                for (int off = 1; off < 16; off <<= 1)
#pragma unroll
                    for (int r = 0; r < 4; ++r) { s[r] += __shfl_xor(s[r], off); q[r] += __shfl_xor(q[r], off); }
                float mean[4], rstd[4];
#pragma unroll
                for (int r = 0; r < 4; ++r) {
                    mean[r] = s[r] * (1.0f / NOUT);
                    float var = q[r] * (1.0f / NOUT) - mean[r] * mean[r];
                    rstd[r] = rsqrtf(var + 1e-5f);
                }
                ushort* out = (ushort*)(tsel ? a.outv : a.outm);
#pragma unroll
                for (int nt = 0; nt < NT; ++nt) {
                    int n = nt * 16 + r15;
                    float gg = g[n], bb = b[n];
#pragma unroll
                    for (int r = 0; r < 4; ++r) {
                        int row = m0 + t * 16 + kseg * 4 + r;
                        if (row < NN) {
                            float y = fmaxf((acc[tt][t][nt][r] - mean[r]) * rstd[r] * gg + bb, 0.0f);
                            out[(size_t)row * NOUT + n] = f2b(y);
                        }
                    }
                }
            }
        } else {
            float* out = (float*)(tsel ? a.outv : a.outm);
#pragma unroll
            for (int t = 0; t < 2; ++t)
#pragma unroll
                for (int nt = 0; nt < NT; ++nt) {
                    int n = nt * 16 + r15;
#pragma unroll
                    for (int r = 0; r < 4; ++r) {
                        int row = m0 + t * 16 + kseg * 4 + r;
                        if (row < NN) out[(size_t)row * NOUT + n] = acc[tt][t][nt][r];
                    }
                }
        }
    }
}

// ---------------- launch ----------------

extern "C" void kernel_launch(void* const* d_in, const int* in_sizes, int n_in,
                              void* d_out, int out_size, void* d_ws, size_t ws_size,
                              hipStream_t stream) {
    const float* x = (const float*)d_in[0];
    const int* ei = (const int*)d_in[1];
    const int* esrc = ei;
    const int* edst = ei + NE;

    const float* mWl0 = (const float*)d_in[2];
    const float* mbl0 = (const float*)d_in[3];
    const float* mWr0 = (const float*)d_in[4];
    const float* mg0  = (const float*)d_in[5];
    const float* mb0  = (const float*)d_in[6];
    const float* mWl1 = (const float*)d_in[7];
    const float* mbl1 = (const float*)d_in[8];
    const float* mWr1 = (const float*)d_in[9];
    const float* mg1  = (const float*)d_in[10];
    const float* mb1  = (const float*)d_in[11];
    const float* mWl2 = (const float*)d_in[12];
    const float* mbl2 = (const float*)d_in[13];
    const float* mWr2 = (const float*)d_in[14];
    const float* vWl0 = (const float*)d_in[15];
    const float* vbl0 = (const float*)d_in[16];
    const float* vWr0 = (const float*)d_in[17];
    const float* vg0  = (const float*)d_in[18];
    const float* vb0  = (const float*)d_in[19];
    const float* vWl1 = (const float*)d_in[20];
    const float* vbl1 = (const float*)d_in[21];
    const float* vWr1 = (const float*)d_in[22];
    const float* vg1  = (const float*)d_in[23];
    const float* vb1  = (const float*)d_in[24];
    const float* vWl2 = (const float*)d_in[25];
    const float* vbl2 = (const float*)d_in[26];
    const float* vWr2 = (const float*)d_in[27];

    char* p = (char*)d_ws;
    auto alloc = [&](size_t bytes) {
        void* r = (void*)p;
        p += (bytes + 255) & ~(size_t)255;
        return r;
    };
    int* deg       = (int*)alloc((size_t)NN * 4);
    int* part      = (int*)alloc((size_t)SCAN_NB * 4);
    int* row_start = (int*)alloc((size_t)(NN + 1) * 4);
    int* cursor    = (int*)alloc((size_t)NN * 4);
    int* col       = (int*)alloc((size_t)NE * 4);
    float* inv_deg = (float*)alloc((size_t)NN * 4);
    ushort* x_bf   = (ushort*)alloc((size_t)MPAD * 64 * 2);
    ushort* agg0   = (ushort*)alloc((size_t)MPAD * 64 * 2);
    ushort* h1m    = (ushort*)alloc((size_t)MPAD * 128 * 2);
    ushort* h1v    = (ushort*)alloc((size_t)MPAD * 128 * 2);
    ushort* h2m    = (ushort*)alloc((size_t)MPAD * 128 * 2);
    ushort* h2v    = (ushort*)alloc((size_t)MPAD * 128 * 2);
    ushort* aggm   = (ushort*)alloc((size_t)MPAD * 128 * 2);
    ushort* aggv   = (ushort*)alloc((size_t)MPAD * 128 * 2);
    ushort* wc0    = (ushort*)alloc((size_t)128 * 128 * 2);
    ushort* wc1    = (ushort*)alloc((size_t)128 * 256 * 2);
    ushort* wc2    = (ushort*)alloc((size_t)64 * 256 * 2);
    ushort* wc3    = (ushort*)alloc((size_t)128 * 128 * 2);
    ushort* wc4    = (ushort*)alloc((size_t)128 * 256 * 2);
    ushort* wc5    = (ushort*)alloc((size_t)64 * 256 * 2);

    float* out_mu = (float*)d_out;
    float* out_lv = (float*)d_out + (size_t)NN * 64;

    // CSR build (parallel 3-phase scan)
    hipMemsetAsync(deg, 0, (size_t)NN * 4, stream);
    k_deg<<<(NE + 255) / 256, 256, 0, stream>>>(edst, deg, NE);
    k_part<<<SCAN_NB, SCAN_BLK, 0, stream>>>(deg, part);
    k_scan_small<<<1, 128, 0, stream>>>(part);
    k_rows<<<SCAN_NB, SCAN_BLK, 0, stream>>>(deg, part, row_start, cursor, inv_deg);
    k_fill<<<(NE + 255) / 256, 256, 0, stream>>>(esrc, edst, cursor, col, NE);

    // conversions
    k_xcvt<<<(NN * 64 / 2 + 255) / 256, 256, 0, stream>>>(x, x_bf, NN * 64 / 2);
    WArgs wa;
    wa.wl[0] = mWl0; wa.wr[0] = mWr0; wa.wc[0] = wc0;
    wa.wl[1] = mWl1; wa.wr[1] = mWr1; wa.wc[1] = wc1;
    wa.wl[2] = mWl2; wa.wr[2] = mWr2; wa.wc[2] = wc2;
    wa.wl[3] = vWl0; wa.wr[3] = vWr0; wa.wc[3] = wc3;
    wa.wl[4] = vWl1; wa.wr[4] = vWr1; wa.wc[4] = wc4;
    wa.wl[5] = vWl2; wa.wr[5] = vWr2; wa.wc[5] = wc5;
    k_wcvt<<<512, 256, 0, stream>>>(wa);

    const int gA = (NN * 16 + 255) / 256;  // 16-lane group per node
    const int gM = MPAD / 128;             // 391

    // layer 0: one gather of x; DUAL GEMM (both towers, one A pass)
    k_agg<64><<<gA, 256, 0, stream>>>(x_bf, row_start, col, inv_deg, agg0);
    {
        GArgs ga = {agg0, agg0, x_bf, x_bf, wc0, wc3,
                    mbl0, vbl0, mg0, vg0, mb0, vb0, h1m, h1v};
        k_gemm<64, 128, true, true><<<dim3(gM, 1), 256, 0, stream>>>(ga);
    }
    // layer 1
    k_agg<128><<<gA, 256, 0, stream>>>(h1m, row_start, col, inv_deg, aggm);
    k_agg<128><<<gA, 256, 0, stream>>>(h1v, row_start, col, inv_deg, aggv);
    {
        GArgs ga = {aggm, aggv, h1m, h1v, wc1, wc4,
                    mbl1, vbl1, mg1, vg1, mb1, vb1, h2m, h2v};
        k_gemm<128, 128, true, false><<<dim3(gM, 2), 256, 0, stream>>>(ga);
    }
    // layer 2 (final, fp32 out, no LN)
    k_agg<128><<<gA, 256, 0, stream>>>(h2m, row_start, col, inv_deg, aggm);
    k_agg<128><<<gA, 256, 0, stream>>>(h2v, row_start, col, inv_deg, aggv);
    {
        GArgs ga = {aggm, aggv, h2m, h2v, wc2, wc5,
                    mbl2, vbl2, nullptr, nullptr, nullptr, nullptr, out_mu, out_lv};
        k_gemm<128, 64, false, false><<<dim3(gM, 2), 256, 0, stream>>>(ga);
    }
}

// Round 7
// 420.146 us; speedup vs baseline: 1.6686x; 1.0416x over previous
//
#include <hip/hip_runtime.h>

#define NN 50000
#define NE 800000
#define MPAD 50048   // 391 * 128
#define SCAN_BLK 512
#define SCAN_NB 98   // ceil(NN/512)

typedef __attribute__((ext_vector_type(8))) short short8;
typedef __attribute__((ext_vector_type(4))) float f32x4;

__device__ __forceinline__ ushort f2b(float f) {
    uint u = __builtin_bit_cast(uint, f);
    uint r = (u + 0x7fffu + ((u >> 16) & 1u)) >> 16;
    return (ushort)r;
}
__device__ __forceinline__ uint pk2(float a, float b) {
    return (uint)f2b(a) | ((uint)f2b(b) << 16);
}
__device__ __forceinline__ float blo(uint u) { return __builtin_bit_cast(float, u << 16); }
__device__ __forceinline__ float bhi(uint u) { return __builtin_bit_cast(float, u & 0xffff0000u); }

// ---------------- CSR build ----------------

__global__ void k_deg(const int* __restrict__ dst, int* __restrict__ deg, int e4) {
    int i = (blockIdx.x * blockDim.x + threadIdx.x);
    if (i < e4) {
        int4 d = *(const int4*)(dst + i * 4);
        atomicAdd(&deg[d.x], 1);
        atomicAdd(&deg[d.y], 1);
        atomicAdd(&deg[d.z], 1);
        atomicAdd(&deg[d.w], 1);
    }
}

__global__ __launch_bounds__(SCAN_BLK) void k_part(const int* __restrict__ deg,
                                                   int* __restrict__ part) {
    __shared__ int s[SCAN_BLK];
    int i = blockIdx.x * SCAN_BLK + threadIdx.x;
    s[threadIdx.x] = (i < NN) ? deg[i] : 0;
    __syncthreads();
#pragma unroll
    for (int off = SCAN_BLK / 2; off > 0; off >>= 1) {
        if (threadIdx.x < off) s[threadIdx.x] += s[threadIdx.x + off];
        __syncthreads();
    }
    if (threadIdx.x == 0) part[blockIdx.x] = s[0];
}

__global__ __launch_bounds__(128) void k_scan_small(int* __restrict__ part) {
    __shared__ int s[128];
    int tid = threadIdx.x;
    int v = (tid < SCAN_NB) ? part[tid] : 0;
    s[tid] = v;
    __syncthreads();
#pragma unroll
    for (int off = 1; off < 128; off <<= 1) {
        int t = (tid >= off) ? s[tid - off] : 0;
        __syncthreads();
        s[tid] += t;
        __syncthreads();
    }
    if (tid < SCAN_NB) part[tid] = s[tid] - v;
}

__global__ __launch_bounds__(SCAN_BLK) void k_rows(const int* __restrict__ deg,
                                                   const int* __restrict__ part,
                                                   int* __restrict__ row_start,
                                                   int* __restrict__ cursor,
                                                   float* __restrict__ inv_deg) {
    __shared__ int s[SCAN_BLK];
    int i = blockIdx.x * SCAN_BLK + threadIdx.x;
    int d = (i < NN) ? deg[i] : 0;
    s[threadIdx.x] = d;
    __syncthreads();
#pragma unroll
    for (int off = 1; off < SCAN_BLK; off <<= 1) {
        int t = (threadIdx.x >= off) ? s[threadIdx.x - off] : 0;
        __syncthreads();
        s[threadIdx.x] += t;
        __syncthreads();
    }
    int excl = s[threadIdx.x] - d + part[blockIdx.x];
    if (i < NN) {
        row_start[i] = excl;
        cursor[i] = excl;
        inv_deg[i] = 1.0f / (float)(d > 1 ? d : 1);
        if (i == NN - 1) row_start[NN] = excl + d;
    }
}

// 4 edges per thread: 4 independent atomic->store chains in flight
__global__ void k_fill(const int* __restrict__ src, const int* __restrict__ dst,
                       int* __restrict__ cursor, int* __restrict__ col, int e4) {
    int i = blockIdx.x * blockDim.x + threadIdx.x;
    if (i < e4) {
        int4 d = *(const int4*)(dst + i * 4);
        int4 s = *(const int4*)(src + i * 4);
        int p0 = atomicAdd(&cursor[d.x], 1);
        int p1 = atomicAdd(&cursor[d.y], 1);
        int p2 = atomicAdd(&cursor[d.z], 1);
        int p3 = atomicAdd(&cursor[d.w], 1);
        col[p0] = s.x;
        col[p1] = s.y;
        col[p2] = s.z;
        col[p3] = s.w;
    }
}

// ---------------- conversions ----------------

__global__ void k_xcvt(const float* __restrict__ x, ushort* __restrict__ xb, int n2) {
    int i = blockIdx.x * blockDim.x + threadIdx.x;
    if (i < n2) {
        float2 v = *(const float2*)(x + (size_t)i * 2);
        *(uint*)(xb + (size_t)i * 2) = pk2(v.x, v.y);
    }
}

// 8 weight blobs in MFMA fragment-stream order.
// elem (row n, col c of K-dim KK): ks=c>>5, kseg=(c>>3)&3, j=c&7, nt=n>>4, r15=n&15,
// lane=kseg*16+r15, off = ((ks*NT+nt)*64 + lane)*8 + j
struct W2Args {
    const float* srcA[8];   // Wl (first `split` cols) or null
    const float* srcB[8];   // Wr (remaining cols) or null
    ushort* dst[8];
};

__global__ void k_wcvt(W2Args a) {
    const int offT[8]   = {0, 16384, 49152, 57344, 65536, 81920, 114688, 122880};
    const int splitT[8] = {64, 128, 128, 0, 64, 128, 128, 0};
    const int logKKT[8] = {7, 8, 7, 7, 7, 8, 7, 7};
    const int ntT[8]    = {8, 8, 4, 4, 8, 8, 4, 4};
    int idx = blockIdx.x * blockDim.x + threadIdx.x;
    if (idx >= 131072) return;
    int L = 0;
#pragma unroll
    for (int i = 1; i < 8; ++i) if (idx >= offT[i]) L = i;
    int j = idx - offT[L];
    int lk = logKKT[L];
    int KK = 1 << lk;
    int n = j >> lk;
    int c = j & (KK - 1);
    int split = splitT[L];
    float v = (c < split) ? a.srcA[L][n * split + c]
                          : a.srcB[L][n * (KK - split) + (c - split)];
    int ks = c >> 5, kseg = (c >> 3) & 3, jj = c & 7;
    int nt = n >> 4, r15 = n & 15;
    int lane = (kseg << 4) | r15;
    int foff = ((ks * ntT[L] + nt) << 9) + (lane << 3) + jj;
    a.dst[L][foff] = f2b(v);
}

// ---------------- mean aggregation: 16-lane group per node, 8-edge unroll ----------------

__device__ __forceinline__ void acc8(float* a, uint4 u) {
    a[0] += blo(u.x); a[1] += bhi(u.x);
    a[2] += blo(u.y); a[3] += bhi(u.y);
    a[4] += blo(u.z); a[5] += bhi(u.z);
    a[6] += blo(u.w); a[7] += bhi(u.w);
}
__device__ __forceinline__ void acc4(float* a, uint2 u) {
    a[0] += blo(u.x); a[1] += bhi(u.x);
    a[2] += blo(u.y); a[3] += bhi(u.y);
}

template <int D>
__global__ __launch_bounds__(256) void k_agg(
    const ushort* __restrict__ h,
    const int* __restrict__ row_start, const int* __restrict__ col,
    const float* __restrict__ inv_deg, ushort* __restrict__ o) {
    int node = (blockIdx.x * 256 + threadIdx.x) >> 4;
    int li = threadIdx.x & 15;
    if (node >= NN) return;
    int s = row_start[node], e = row_start[node + 1];
    float sc = inv_deg[node];
    if (D == 128) {
        const ushort* hb = h + (size_t)li * 8;
        float a[8] = {0, 0, 0, 0, 0, 0, 0, 0};
        int p = s;
        for (; p + 7 < e; p += 8) {
            int c0 = col[p], c1 = col[p + 1], c2 = col[p + 2], c3 = col[p + 3];
            int c4 = col[p + 4], c5 = col[p + 5], c6 = col[p + 6], c7 = col[p + 7];
            uint4 u0 = *(const uint4*)(hb + (size_t)c0 * 128);
            uint4 u1 = *(const uint4*)(hb + (size_t)c1 * 128);
            uint4 u2 = *(const uint4*)(hb + (size_t)c2 * 128);
            uint4 u3 = *(const uint4*)(hb + (size_t)c3 * 128);
            uint4 u4 = *(const uint4*)(hb + (size_t)c4 * 128);
            uint4 u5 = *(const uint4*)(hb + (size_t)c5 * 128);
            uint4 u6 = *(const uint4*)(hb + (size_t)c6 * 128);
            uint4 u7 = *(const uint4*)(hb + (size_t)c7 * 128);
            acc8(a, u0); acc8(a, u1); acc8(a, u2); acc8(a, u3);
            acc8(a, u4); acc8(a, u5); acc8(a, u6); acc8(a, u7);
        }
        for (; p + 3 < e; p += 4) {
            int c0 = col[p], c1 = col[p + 1], c2 = col[p + 2], c3 = col[p + 3];
            uint4 u0 = *(const uint4*)(hb + (size_t)c0 * 128);
            uint4 u1 = *(const uint4*)(hb + (size_t)c1 * 128);
            uint4 u2 = *(const uint4*)(hb + (size_t)c2 * 128);
            uint4 u3 = *(const uint4*)(hb + (size_t)c3 * 128);
            acc8(a, u0); acc8(a, u1); acc8(a, u2); acc8(a, u3);
        }
        for (; p < e; ++p) acc8(a, *(const uint4*)(hb + (size_t)col[p] * 128));
        uint4 r;
        r.x = pk2(a[0] * sc, a[1] * sc);
        r.y = pk2(a[2] * sc, a[3] * sc);
        r.z = pk2(a[4] * sc, a[5] * sc);
        r.w = pk2(a[6] * sc, a[7] * sc);
        *(uint4*)(o + (size_t)node * 128 + li * 8) = r;
    } else {
        const ushort* hb = h + (size_t)li * 4;
        float a[4] = {0, 0, 0, 0};
        int p = s;
        for (; p + 7 < e; p += 8) {
            int c0 = col[p], c1 = col[p + 1], c2 = col[p + 2], c3 = col[p + 3];
            int c4 = col[p + 4], c5 = col[p + 5], c6 = col[p + 6], c7 = col[p + 7];
            uint2 u0 = *(const uint2*)(hb + (size_t)c0 * 64);
            uint2 u1 = *(const uint2*)(hb + (size_t)c1 * 64);
            uint2 u2 = *(const uint2*)(hb + (size_t)c2 * 64);
            uint2 u3 = *(const uint2*)(hb + (size_t)c3 * 64);
            uint2 u4 = *(const uint2*)(hb + (size_t)c4 * 64);
            uint2 u5 = *(const uint2*)(hb + (size_t)c5 * 64);
            uint2 u6 = *(const uint2*)(hb + (size_t)c6 * 64);
            uint2 u7 = *(const uint2*)(hb + (size_t)c7 * 64);
            acc4(a, u0); acc4(a, u1); acc4(a, u2); acc4(a, u3);
            acc4(a, u4); acc4(a, u5); acc4(a, u6); acc4(a, u7);
        }
        for (; p + 3 < e; p += 4) {
            int c0 = col[p], c1 = col[p + 1], c2 = col[p + 2], c3 = col[p + 3];
            uint2 u0 = *(const uint2*)(hb + (size_t)c0 * 64);
            uint2 u1 = *(const uint2*)(hb + (size_t)c1 * 64);
            uint2 u2 = *(const uint2*)(hb + (size_t)c2 * 64);
            uint2 u3 = *(const uint2*)(hb + (size_t)c3 * 64);
            acc4(a, u0); acc4(a, u1); acc4(a, u2); acc4(a, u3);
        }
        for (; p < e; ++p) acc4(a, *(const uint2*)(hb + (size_t)col[p] * 64));
        uint2 r;
        r.x = pk2(a[0] * sc, a[1] * sc);
        r.y = pk2(a[2] * sc, a[3] * sc);
        *(uint2*)(o + (size_t)node * 64 + li * 4) = r;
    }
}

// ---------------- MFMA GEMM with LDS-resident fragment-ordered W (L0/L1) ----------------

struct GArgs {
    const ushort *A1m, *A1v, *A2m, *A2v, *Wm, *Wv;
    const float *blm, *blv, *gm, *gv, *bbm, *bbv;
    void *outm, *outv;
};

template <int KH, int NOUT, bool DO_LN, bool DUAL>
__global__ __launch_bounds__(256, 2) void k_gemm(GArgs a) {
    constexpr int NT = NOUT / 16;
    constexpr int NK = KH / 16;
    constexpr int TW = DUAL ? 2 : 1;
    constexpr int WCH = NOUT * KH * 4 / 16;
    __shared__ uint4 wlds[TW * WCH];

    int tid = threadIdx.x;
    int lane = tid & 63, wid = tid >> 6;
    int tow = DUAL ? 0 : blockIdx.y;
    const ushort* A1 = tow ? a.A1v : a.A1m;
    const ushort* A2 = tow ? a.A2v : a.A2m;

    {
        const uint4* w0 = (const uint4*)(tow ? a.Wv : a.Wm);
        for (int i = tid; i < WCH; i += 256) wlds[i] = w0[i];
        if (DUAL) {
            const uint4* w1 = (const uint4*)a.Wv;
            for (int i = tid; i < WCH; i += 256) wlds[WCH + i] = w1[i];
        }
    }

    int r15 = lane & 15, kseg = lane >> 4;
    int m0 = blockIdx.x * 128 + wid * 32;
    size_t ar0 = (size_t)(m0 + r15);
    size_t ar1 = (size_t)(m0 + 16 + r15);

    short8 af[2][NK];
#pragma unroll
    for (int ks = 0; ks < NK; ++ks) {
        int kc = ks * 32 + kseg * 8;
        af[0][ks] = (kc < KH) ? *(const short8*)(A1 + ar0 * KH + kc)
                              : *(const short8*)(A2 + ar0 * KH + (kc - KH));
        af[1][ks] = (kc < KH) ? *(const short8*)(A1 + ar1 * KH + kc)
                              : *(const short8*)(A2 + ar1 * KH + (kc - KH));
    }
    __syncthreads();

    f32x4 acc[TW][2][NT];
#pragma unroll
    for (int tt = 0; tt < TW; ++tt)
#pragma unroll
        for (int t = 0; t < 2; ++t)
#pragma unroll
            for (int nt = 0; nt < NT; ++nt) acc[tt][t][nt] = (f32x4){0.f, 0.f, 0.f, 0.f};

#pragma unroll
    for (int ks = 0; ks < NK; ++ks) {
#pragma unroll
        for (int nt = 0; nt < NT; ++nt) {
#pragma unroll
            for (int tt = 0; tt < TW; ++tt) {
                short8 w = *(const short8*)&wlds[tt * WCH + (ks * NT + nt) * 64 + lane];
                acc[tt][0][nt] = __builtin_amdgcn_mfma_f32_16x16x32_bf16(af[0][ks], w, acc[tt][0][nt], 0, 0, 0);
                acc[tt][1][nt] = __builtin_amdgcn_mfma_f32_16x16x32_bf16(af[1][ks], w, acc[tt][1][nt], 0, 0, 0);
            }
        }
    }

#pragma unroll
    for (int tt = 0; tt < TW; ++tt) {
        int tsel = DUAL ? tt : tow;
        const float* bl = tsel ? a.blv : a.blm;
#pragma unroll
        for (int nt = 0; nt < NT; ++nt) {
            float bb = bl[nt * 16 + r15];
#pragma unroll
            for (int t = 0; t < 2; ++t)
#pragma unroll
                for (int r = 0; r < 4; ++r) acc[tt][t][nt][r] += bb;
        }
        if (DO_LN) {
            const float* g = tsel ? a.gv : a.gm;
            const float* b = tsel ? a.bbv : a.bbm;
#pragma unroll
            for (int t = 0; t < 2; ++t) {
                float s[4] = {0, 0, 0, 0}, q[4] = {0, 0, 0, 0};
#pragma unroll
                for (int nt = 0; nt < NT; ++nt)
#pragma unroll
                    for (int r = 0; r < 4; ++r) { float v = acc[tt][t][nt][r]; s[r] += v; q[r] += v * v; }
#pragma unroll
                for (int off = 1; off < 16; off <<= 1)
#pragma unroll
                    for (int r = 0; r < 4; ++r) { s[r] += __shfl_xor(s[r], off); q[r] += __shfl_xor(q[r], off); }
                float mean[4], rstd[4];
#pragma unroll
                for (int r = 0; r < 4; ++r) {
                    mean[r] = s[r] * (1.0f / NOUT);
                    float var = q[r] * (1.0f / NOUT) - mean[r] * mean[r];
                    rstd[r] = rsqrtf(var + 1e-5f);
                }
                ushort* out = (ushort*)(tsel ? a.outv : a.outm);
#pragma unroll
                for (int nt = 0; nt < NT; ++nt) {
                    int n = nt * 16 + r15;
                    float gg = g[n], bb = b[n];
#pragma unroll
                    for (int r = 0; r < 4; ++r) {
                        int row = m0 + t * 16 + kseg * 4 + r;
                        if (row < NN) {
                            float y = fmaxf((acc[tt][t][nt][r] - mean[r]) * rstd[r] * gg + bb, 0.0f);
                            out[(size_t)row * NOUT + n] = f2b(y);
                        }
                    }
                }
            }
        } else {
            float* out = (float*)(tsel ? a.outv : a.outm);
#pragma unroll
            for (int t = 0; t < 2; ++t)
#pragma unroll
                for (int nt = 0; nt < NT; ++nt) {
                    int n = nt * 16 + r15;
#pragma unroll
                    for (int r = 0; r < 4; ++r) {
                        int row = m0 + t * 16 + kseg * 4 + r;
                        if (row < NN) out[(size_t)row * NOUT + n] = acc[tt][t][nt][r];
                    }
                }
        }
    }
}

// ---------------- layer-2 split kernels (linearity: agg(h)@Wl^T == agg(h@Wl^T)) ----------
// k_gemm2<false>: p2[node][tow*64+n] = bf16( h2 @ Wl2^T )   (no bias)
// k_gemm2<true> : out[node][n] = acc(h2@Wr2^T) + bl[n] + a2[node][tow*64+n]

struct G2Args {
    const ushort *Am, *Av, *Wm, *Wv, *a2;
    const float *blm, *blv;
    void *outm, *outv;
};

template <bool FINAL>
__global__ __launch_bounds__(256, 2) void k_gemm2(G2Args a) {
    constexpr int NT = 4, NK = 4;
    constexpr int WCH = 1024;  // 16KB
    __shared__ uint4 wlds[WCH];

    int tid = threadIdx.x;
    int lane = tid & 63, wid = tid >> 6;
    int tow = blockIdx.y;
    const ushort* A = tow ? a.Av : a.Am;
    {
        const uint4* w0 = (const uint4*)(tow ? a.Wv : a.Wm);
        for (int i = tid; i < WCH; i += 256) wlds[i] = w0[i];
    }
    int r15 = lane & 15, kseg = lane >> 4;
    int m0 = blockIdx.x * 128 + wid * 32;
    size_t ar0 = (size_t)(m0 + r15);
    size_t ar1 = (size_t)(m0 + 16 + r15);

    short8 af[2][NK];
#pragma unroll
    for (int ks = 0; ks < NK; ++ks) {
        int kc = ks * 32 + kseg * 8;
        af[0][ks] = *(const short8*)(A + ar0 * 128 + kc);
        af[1][ks] = *(const short8*)(A + ar1 * 128 + kc);
    }
    __syncthreads();

    f32x4 acc[2][NT];
#pragma unroll
    for (int t = 0; t < 2; ++t)
#pragma unroll
        for (int nt = 0; nt < NT; ++nt) acc[t][nt] = (f32x4){0.f, 0.f, 0.f, 0.f};

#pragma unroll
    for (int ks = 0; ks < NK; ++ks) {
#pragma unroll
        for (int nt = 0; nt < NT; ++nt) {
            short8 w = *(const short8*)&wlds[(ks * NT + nt) * 64 + lane];
            acc[0][nt] = __builtin_amdgcn_mfma_f32_16x16x32_bf16(af[0][ks], w, acc[0][nt], 0, 0, 0);
            acc[1][nt] = __builtin_amdgcn_mfma_f32_16x16x32_bf16(af[1][ks], w, acc[1][nt], 0, 0, 0);
        }
    }

    if (FINAL) {
        const float* bl = tow ? a.blv : a.blm;
        float* out = (float*)(tow ? a.outv : a.outm);
#pragma unroll
        for (int t = 0; t < 2; ++t)
#pragma unroll
            for (int nt = 0; nt < NT; ++nt) {
                int n = nt * 16 + r15;
                float bb = bl[n];
#pragma unroll
                for (int r = 0; r < 4; ++r) {
                    int row = m0 + t * 16 + kseg * 4 + r;
                    if (row < NN) {
                        float av = blo((uint)a.a2[(size_t)row * 128 + tow * 64 + n]);
                        out[(size_t)row * 64 + n] = acc[t][nt][r] + bb + av;
                    }
                }
            }
    } else {
        ushort* out = (ushort*)a.outm;
#pragma unroll
        for (int t = 0; t < 2; ++t)
#pragma unroll
            for (int nt = 0; nt < NT; ++nt) {
                int n = nt * 16 + r15;
#pragma unroll
                for (int r = 0; r < 4; ++r) {
                    int row = m0 + t * 16 + kseg * 4 + r;
                    if (row < NN) out[(size_t)row * 128 + tow * 64 + n] = f2b(acc[t][nt][r]);
                }
            }
    }
}

// ---------------- launch ----------------

extern "C" void kernel_launch(void* const* d_in, const int* in_sizes, int n_in,
                              void* d_out, int out_size, void* d_ws, size_t ws_size,
                              hipStream_t stream) {
    const float* x = (const float*)d_in[0];
    const int* ei = (const int*)d_in[1];
    const int* esrc = ei;
    const int* edst = ei + NE;

    const float* mWl0 = (const float*)d_in[2];
    const float* mbl0 = (const float*)d_in[3];
    const float* mWr0 = (const float*)d_in[4];
    const float* mg0  = (const float*)d_in[5];
    const float* mb0  = (const float*)d_in[6];
    const float* mWl1 = (const float*)d_in[7];
    const float* mbl1 = (const float*)d_in[8];
    const float* mWr1 = (const float*)d_in[9];
    const float* mg1  = (const float*)d_in[10];
    const float* mb1  = (const float*)d_in[11];
    const float* mWl2 = (const float*)d_in[12];
    const float* mbl2 = (const float*)d_in[13];
    const float* mWr2 = (const float*)d_in[14];
    const float* vWl0 = (const float*)d_in[15];
    const float* vbl0 = (const float*)d_in[16];
    const float* vWr0 = (const float*)d_in[17];
    const float* vg0  = (const float*)d_in[18];
    const float* vb0  = (const float*)d_in[19];
    const float* vWl1 = (const float*)d_in[20];
    const float* vbl1 = (const float*)d_in[21];
    const float* vWr1 = (const float*)d_in[22];
    const float* vg1  = (const float*)d_in[23];
    const float* vb1  = (const float*)d_in[24];
    const float* vWl2 = (const float*)d_in[25];
    const float* vbl2 = (const float*)d_in[26];
    const float* vWr2 = (const float*)d_in[27];

    char* p = (char*)d_ws;
    auto alloc = [&](size_t bytes) {
        void* r = (void*)p;
        p += (bytes + 255) & ~(size_t)255;
        return r;
    };
    int* deg       = (int*)alloc((size_t)NN * 4);
    int* part      = (int*)alloc((size_t)SCAN_NB * 4);
    int* row_start = (int*)alloc((size_t)(NN + 1) * 4);
    int* cursor    = (int*)alloc((size_t)NN * 4);
    int* col       = (int*)alloc((size_t)NE * 4);
    float* inv_deg = (float*)alloc((size_t)NN * 4);
    ushort* x_bf   = (ushort*)alloc((size_t)MPAD * 64 * 2);
    ushort* agg0   = (ushort*)alloc((size_t)MPAD * 64 * 2);
    ushort* h1m    = (ushort*)alloc((size_t)MPAD * 128 * 2);
    ushort* h1v    = (ushort*)alloc((size_t)MPAD * 128 * 2);
    ushort* h2m    = (ushort*)alloc((size_t)MPAD * 128 * 2);
    ushort* h2v    = (ushort*)alloc((size_t)MPAD * 128 * 2);
    ushort* p2     = (ushort*)alloc((size_t)MPAD * 128 * 2);
    ushort* a2     = (ushort*)alloc((size_t)MPAD * 128 * 2);
    ushort* wc0    = (ushort*)alloc((size_t)128 * 128 * 2);
    ushort* wc1    = (ushort*)alloc((size_t)128 * 256 * 2);
    ushort* wc2    = (ushort*)alloc((size_t)64 * 128 * 2);
    ushort* wc3    = (ushort*)alloc((size_t)128 * 128 * 2);
    ushort* wc4    = (ushort*)alloc((size_t)128 * 256 * 2);
    ushort* wc5    = (ushort*)alloc((size_t)64 * 128 * 2);
    ushort* wc6    = (ushort*)alloc((size_t)64 * 128 * 2);
    ushort* wc7    = (ushort*)alloc((size_t)64 * 128 * 2);

    float* out_mu = (float*)d_out;
    float* out_lv = (float*)d_out + (size_t)NN * 64;

    // CSR build (parallel 3-phase scan)
    hipMemsetAsync(deg, 0, (size_t)NN * 4, stream);
    k_deg<<<(NE / 4 + 255) / 256, 256, 0, stream>>>(edst, deg, NE / 4);
    k_part<<<SCAN_NB, SCAN_BLK, 0, stream>>>(deg, part);
    k_scan_small<<<1, 128, 0, stream>>>(part);
    k_rows<<<SCAN_NB, SCAN_BLK, 0, stream>>>(deg, part, row_start, cursor, inv_deg);
    k_fill<<<(NE / 4 + 255) / 256, 256, 0, stream>>>(esrc, edst, cursor, col, NE / 4);

    // conversions
    k_xcvt<<<(NN * 64 / 2 + 255) / 256, 256, 0, stream>>>(x, x_bf, NN * 64 / 2);
    W2Args wa;
    wa.srcA[0] = mWl0; wa.srcB[0] = mWr0; wa.dst[0] = wc0;
    wa.srcA[1] = mWl1; wa.srcB[1] = mWr1; wa.dst[1] = wc1;
    wa.srcA[2] = mWl2; wa.srcB[2] = nullptr; wa.dst[2] = wc2;
    wa.srcA[3] = nullptr; wa.srcB[3] = mWr2; wa.dst[3] = wc6;
    wa.srcA[4] = vWl0; wa.srcB[4] = vWr0; wa.dst[4] = wc3;
    wa.srcA[5] = vWl1; wa.srcB[5] = vWr1; wa.dst[5] = wc4;
    wa.srcA[6] = vWl2; wa.srcB[6] = nullptr; wa.dst[6] = wc5;
    wa.srcA[7] = nullptr; wa.srcB[7] = vWr2; wa.dst[7] = wc7;
    k_wcvt<<<512, 256, 0, stream>>>(wa);

    const int gA = (NN * 16 + 255) / 256;  // 16-lane group per node
    const int gM = MPAD / 128;             // 391

    // layer 0: one gather of x; DUAL GEMM (both towers, one A pass)
    k_agg<64><<<gA, 256, 0, stream>>>(x_bf, row_start, col, inv_deg, agg0);
    {
        GArgs ga = {agg0, agg0, x_bf, x_bf, wc0, wc3,
                    mbl0, vbl0, mg0, vg0, mb0, vb0, h1m, h1v};
        k_gemm<64, 128, true, true><<<dim3(gM, 1), 256, 0, stream>>>(ga);
    }
    // layer 1
    k_agg<128><<<gA, 256, 0, stream>>>(h1m, row_start, col, inv_deg, p2);   // reuse p2 as aggm
    k_agg<128><<<gA, 256, 0, stream>>>(h1v, row_start, col, inv_deg, a2);   // reuse a2 as aggv
    {
        GArgs ga = {p2, a2, h1m, h1v, wc1, wc4,
                    mbl1, vbl1, mg1, vg1, mb1, vb1, h2m, h2v};
        k_gemm<128, 128, true, false><<<dim3(gM, 2), 256, 0, stream>>>(ga);
    }
    // layer 2 via linearity: project (Wl) -> pack -> single agg -> final (Wr + agg + bias)
    {
        G2Args g2 = {h2m, h2v, wc2, wc5, nullptr, nullptr, nullptr, p2, nullptr};
        k_gemm2<false><<<dim3(gM, 2), 256, 0, stream>>>(g2);
    }
    k_agg<128><<<gA, 256, 0, stream>>>(p2, row_start, col, inv_deg, a2);
    {
        G2Args g2 = {h2m, h2v, wc6, wc7, a2, mbl2, vbl2, out_mu, out_lv};
        k_gemm2<true><<<dim3(gM, 2), 256, 0, stream>>>(g2);
    }
}

// Round 8
// 359.042 us; speedup vs baseline: 1.9526x; 1.1702x over previous
//
#include <hip/hip_runtime.h>

#define NN 50000
#define NE 800000
#define MPAD 50048    // 391 * 128
#define NBK 196       // buckets of 256 nodes
#define FB 98         // partition blocks
#define CH4 2048      // int4 per partition block (8192 edges)
#define EB4 200000    // NE/4
#define STAGE_CAP 6144

typedef __attribute__((ext_vector_type(8))) short short8;
typedef __attribute__((ext_vector_type(4))) float f32x4;

__device__ __forceinline__ ushort f2b(float f) {
    uint u = __builtin_bit_cast(uint, f);
    uint r = (u + 0x7fffu + ((u >> 16) & 1u)) >> 16;
    return (ushort)r;
}
__device__ __forceinline__ uint pk2(float a, float b) {
    return (uint)f2b(a) | ((uint)f2b(b) << 16);
}
__device__ __forceinline__ float blo(uint u) { return __builtin_bit_cast(float, u << 16); }
__device__ __forceinline__ float bhi(uint u) { return __builtin_bit_cast(float, u & 0xffff0000u); }

// ================= bucketed CSR build =================
// F1: per-block bucket histogram
__global__ __launch_bounds__(256) void k_f1(const int* __restrict__ dst, int* __restrict__ bhist) {
    __shared__ int h[NBK];
    for (int i = threadIdx.x; i < NBK; i += 256) h[i] = 0;
    __syncthreads();
    int i1 = min((int)(blockIdx.x + 1) * CH4, EB4);
    for (int i = blockIdx.x * CH4 + threadIdx.x; i < i1; i += 256) {
        int4 d = ((const int4*)dst)[i];
        atomicAdd(&h[d.x >> 8], 1);
        atomicAdd(&h[d.y >> 8], 1);
        atomicAdd(&h[d.z >> 8], 1);
        atomicAdd(&h[d.w >> 8], 1);
    }
    __syncthreads();
    for (int i = threadIdx.x; i < NBK; i += 256) bhist[blockIdx.x * NBK + i] = h[i];
}

// Fscan: bucket bases + per-(block,bucket) relative offsets
__global__ __launch_bounds__(256) void k_fscan(const int* __restrict__ bhist,
                                               int* __restrict__ pairRel,
                                               int* __restrict__ bbase) {
    __shared__ int tot[256];
    int b = threadIdx.x;
    int run = 0;
    if (b < NBK) {
        for (int blk = 0; blk < FB; ++blk) {
            int v = bhist[blk * NBK + b];
            pairRel[blk * NBK + b] = run;
            run += v;
        }
    }
    tot[b] = (b < NBK) ? run : 0;
    __syncthreads();
    for (int off = 1; off < 256; off <<= 1) {
        int t = (b >= off) ? tot[b - off] : 0;
        __syncthreads();
        tot[b] += t;
        __syncthreads();
    }
    if (b < NBK) bbase[b] = tot[b] - run;
    if (b == NBK - 1) bbase[NBK] = tot[b];
}

// F2: partition (src,dst) pairs into bucket regions (mostly full-line writes)
__global__ __launch_bounds__(256) void k_f2(const int* __restrict__ src, const int* __restrict__ dst,
                                            const int* __restrict__ pairRel,
                                            const int* __restrict__ bbase, int2* __restrict__ pairs) {
    __shared__ int cur[NBK];
    for (int i = threadIdx.x; i < NBK; i += 256)
        cur[i] = bbase[i] + pairRel[blockIdx.x * NBK + i];
    __syncthreads();
    int i1 = min((int)(blockIdx.x + 1) * CH4, EB4);
    for (int i = blockIdx.x * CH4 + threadIdx.x; i < i1; i += 256) {
        int4 s = ((const int4*)src)[i];
        int4 d = ((const int4*)dst)[i];
        int p0 = atomicAdd(&cur[d.x >> 8], 1);
        int p1 = atomicAdd(&cur[d.y >> 8], 1);
        int p2 = atomicAdd(&cur[d.z >> 8], 1);
        int p3 = atomicAdd(&cur[d.w >> 8], 1);
        pairs[p0] = (int2){s.x, d.x};
        pairs[p1] = (int2){s.y, d.y};
        pairs[p2] = (int2){s.z, d.z};
        pairs[p3] = (int2){s.w, d.w};
    }
}

// F3: per-bucket node histogram + scan -> row_start/inv_deg; fill col via LDS staging (full-line flush)
__global__ __launch_bounds__(256) void k_f3(const int2* __restrict__ pairs,
                                            const int* __restrict__ bbase,
                                            int* __restrict__ row_start,
                                            float* __restrict__ inv_deg,
                                            int* __restrict__ col) {
    __shared__ int ndeg[256];
    __shared__ int noff[256];
    __shared__ int stage[STAGE_CAP];
    int b = blockIdx.x;
    int base = bbase[b], end = bbase[b + 1];
    int nbase = b << 8;
    int t = threadIdx.x;
    ndeg[t] = 0;
    __syncthreads();
    for (int p = base + t; p < end; p += 256) atomicAdd(&ndeg[pairs[p].y - nbase], 1);
    __syncthreads();
    int d = ndeg[t];
    noff[t] = d;
    __syncthreads();
    for (int off = 1; off < 256; off <<= 1) {
        int v = (t >= off) ? noff[t - off] : 0;
        __syncthreads();
        noff[t] += v;
        __syncthreads();
    }
    int excl = noff[t] - d;
    int node = nbase + t;
    if (node < NN) {
        row_start[node] = base + excl;
        inv_deg[node] = 1.0f / (float)(d > 1 ? d : 1);
    }
    if (b == 0 && t == 0) row_start[NN] = NE;
    __syncthreads();
    noff[t] = excl;  // reuse as cursor
    __syncthreads();
    int cnt = end - base;
    for (int p = base + t; p < end; p += 256) {
        int2 pr = pairs[p];
        int pos = atomicAdd(&noff[pr.y - nbase], 1);
        if (pos < STAGE_CAP) stage[pos] = pr.x;
        else col[base + pos] = pr.x;   // overflow fallback (statistically never)
    }
    __syncthreads();
    int lim = cnt < STAGE_CAP ? cnt : STAGE_CAP;
    for (int i = t; i < lim; i += 256) col[base + i] = stage[i];
}

// ================= conversions =================

__global__ void k_xcvt(const float* __restrict__ x, ushort* __restrict__ xb, int n2) {
    int i = blockIdx.x * blockDim.x + threadIdx.x;
    if (i < n2) {
        float2 v = *(const float2*)(x + (size_t)i * 2);
        *(uint*)(xb + (size_t)i * 2) = pk2(v.x, v.y);
    }
}

struct W2Args {
    const float* srcA[8];
    const float* srcB[8];
    ushort* dst[8];
};

__global__ void k_wcvt(W2Args a) {
    const int offT[8]   = {0, 16384, 49152, 57344, 65536, 81920, 114688, 122880};
    const int splitT[8] = {64, 128, 128, 0, 64, 128, 128, 0};
    const int logKKT[8] = {7, 8, 7, 7, 7, 8, 7, 7};
    const int ntT[8]    = {8, 8, 4, 4, 8, 8, 4, 4};
    int idx = blockIdx.x * blockDim.x + threadIdx.x;
    if (idx >= 131072) return;
    int L = 0;
#pragma unroll
    for (int i = 1; i < 8; ++i) if (idx >= offT[i]) L = i;
    int j = idx - offT[L];
    int lk = logKKT[L];
    int KK = 1 << lk;
    int n = j >> lk;
    int c = j & (KK - 1);
    int split = splitT[L];
    float v = (c < split) ? a.srcA[L][n * split + c]
                          : a.srcB[L][n * (KK - split) + (c - split)];
    int ks = c >> 5, kseg = (c >> 3) & 3, jj = c & 7;
    int nt = n >> 4, r15 = n & 15;
    int lane = (kseg << 4) | r15;
    int foff = ((ks * ntT[L] + nt) << 9) + (lane << 3) + jj;
    a.dst[L][foff] = f2b(v);
}

// ================= mean aggregation =================

__device__ __forceinline__ void acc8(float* a, uint4 u) {
    a[0] += blo(u.x); a[1] += bhi(u.x);
    a[2] += blo(u.y); a[3] += bhi(u.y);
    a[4] += blo(u.z); a[5] += bhi(u.z);
    a[6] += blo(u.w); a[7] += bhi(u.w);
}
__device__ __forceinline__ void acc4(float* a, uint2 u) {
    a[0] += blo(u.x); a[1] += bhi(u.x);
    a[2] += blo(u.y); a[3] += bhi(u.y);
}

// D-wide rows, 16-lane group per node (D=64 -> uint2/lane, D=128 -> uint4/lane)
template <int D>
__global__ __launch_bounds__(256) void k_agg(
    const ushort* __restrict__ h,
    const int* __restrict__ row_start, const int* __restrict__ col,
    const float* __restrict__ inv_deg, ushort* __restrict__ o) {
    int node = (blockIdx.x * 256 + threadIdx.x) >> 4;
    int li = threadIdx.x & 15;
    if (node >= NN) return;
    int s = row_start[node], e = row_start[node + 1];
    float sc = inv_deg[node];
    if (D == 128) {
        const ushort* hb = h + (size_t)li * 8;
        float a[8] = {0, 0, 0, 0, 0, 0, 0, 0};
        int p = s;
        for (; p + 7 < e; p += 8) {
            int c0 = col[p], c1 = col[p + 1], c2 = col[p + 2], c3 = col[p + 3];
            int c4 = col[p + 4], c5 = col[p + 5], c6 = col[p + 6], c7 = col[p + 7];
            uint4 u0 = *(const uint4*)(hb + (size_t)c0 * 128);
            uint4 u1 = *(const uint4*)(hb + (size_t)c1 * 128);
            uint4 u2 = *(const uint4*)(hb + (size_t)c2 * 128);
            uint4 u3 = *(const uint4*)(hb + (size_t)c3 * 128);
            uint4 u4 = *(const uint4*)(hb + (size_t)c4 * 128);
            uint4 u5 = *(const uint4*)(hb + (size_t)c5 * 128);
            uint4 u6 = *(const uint4*)(hb + (size_t)c6 * 128);
            uint4 u7 = *(const uint4*)(hb + (size_t)c7 * 128);
            acc8(a, u0); acc8(a, u1); acc8(a, u2); acc8(a, u3);
            acc8(a, u4); acc8(a, u5); acc8(a, u6); acc8(a, u7);
        }
        for (; p < e; ++p) acc8(a, *(const uint4*)(hb + (size_t)col[p] * 128));
        uint4 r;
        r.x = pk2(a[0] * sc, a[1] * sc);
        r.y = pk2(a[2] * sc, a[3] * sc);
        r.z = pk2(a[4] * sc, a[5] * sc);
        r.w = pk2(a[6] * sc, a[7] * sc);
        *(uint4*)(o + (size_t)node * 128 + li * 8) = r;
    } else {
        const ushort* hb = h + (size_t)li * 4;
        float a[4] = {0, 0, 0, 0};
        int p = s;
        for (; p + 7 < e; p += 8) {
            int c0 = col[p], c1 = col[p + 1], c2 = col[p + 2], c3 = col[p + 3];
            int c4 = col[p + 4], c5 = col[p + 5], c6 = col[p + 6], c7 = col[p + 7];
            uint2 u0 = *(const uint2*)(hb + (size_t)c0 * 64);
            uint2 u1 = *(const uint2*)(hb + (size_t)c1 * 64);
            uint2 u2 = *(const uint2*)(hb + (size_t)c2 * 64);
            uint2 u3 = *(const uint2*)(hb + (size_t)c3 * 64);
            uint2 u4 = *(const uint2*)(hb + (size_t)c4 * 64);
            uint2 u5 = *(const uint2*)(hb + (size_t)c5 * 64);
            uint2 u6 = *(const uint2*)(hb + (size_t)c6 * 64);
            uint2 u7 = *(const uint2*)(hb + (size_t)c7 * 64);
            acc4(a, u0); acc4(a, u1); acc4(a, u2); acc4(a, u3);
            acc4(a, u4); acc4(a, u5); acc4(a, u6); acc4(a, u7);
        }
        for (; p < e; ++p) acc4(a, *(const uint2*)(hb + (size_t)col[p] * 64));
        uint2 r;
        r.x = pk2(a[0] * sc, a[1] * sc);
        r.y = pk2(a[2] * sc, a[3] * sc);
        *(uint2*)(o + (size_t)node * 64 + li * 4) = r;
    }
}

// packed 256-wide rows (both towers), 32-lane group per node
__global__ __launch_bounds__(256) void k_agg256(
    const ushort* __restrict__ h,
    const int* __restrict__ row_start, const int* __restrict__ col,
    const float* __restrict__ inv_deg, ushort* __restrict__ o) {
    int node = (blockIdx.x * 256 + threadIdx.x) >> 5;
    int li = threadIdx.x & 31;
    if (node >= NN) return;
    int s = row_start[node], e = row_start[node + 1];
    float sc = inv_deg[node];
    const ushort* hb = h + (size_t)li * 8;
    float a[8] = {0, 0, 0, 0, 0, 0, 0, 0};
    int p = s;
    for (; p + 7 < e; p += 8) {
        int c0 = col[p], c1 = col[p + 1], c2 = col[p + 2], c3 = col[p + 3];
        int c4 = col[p + 4], c5 = col[p + 5], c6 = col[p + 6], c7 = col[p + 7];
        uint4 u0 = *(const uint4*)(hb + (size_t)c0 * 256);
        uint4 u1 = *(const uint4*)(hb + (size_t)c1 * 256);
        uint4 u2 = *(const uint4*)(hb + (size_t)c2 * 256);
        uint4 u3 = *(const uint4*)(hb + (size_t)c3 * 256);
        uint4 u4 = *(const uint4*)(hb + (size_t)c4 * 256);
        uint4 u5 = *(const uint4*)(hb + (size_t)c5 * 256);
        uint4 u6 = *(const uint4*)(hb + (size_t)c6 * 256);
        uint4 u7 = *(const uint4*)(hb + (size_t)c7 * 256);
        acc8(a, u0); acc8(a, u1); acc8(a, u2); acc8(a, u3);
        acc8(a, u4); acc8(a, u5); acc8(a, u6); acc8(a, u7);
    }
    for (; p < e; ++p) acc8(a, *(const uint4*)(hb + (size_t)col[p] * 256));
    uint4 r;
    r.x = pk2(a[0] * sc, a[1] * sc);
    r.y = pk2(a[2] * sc, a[3] * sc);
    r.z = pk2(a[4] * sc, a[5] * sc);
    r.w = pk2(a[6] * sc, a[7] * sc);
    *(uint4*)(o + (size_t)node * 256 + li * 8) = r;
}

// ================= MFMA GEMM, LDS-resident fragment-ordered W =================
// A = [A1 | A2] rows at stride ASTR with per-tower offset tow*AOFFM.
// Output rows at stride OSTR with per-tower offset tsel*OOFFM.

struct GArgs {
    const ushort *A1, *A2, *Wm, *Wv;
    const float *blm, *blv, *gm, *gv, *bbm, *bbv;
    void* out;
};

template <int KH, int NOUT, bool DO_LN, bool DUAL, int ASTR, int AOFFM, int OSTR, int OOFFM>
__global__ __launch_bounds__(256, 2) void k_gemm(GArgs a) {
    constexpr int NT = NOUT / 16;
    constexpr int NK = KH / 16;
    constexpr int TW = DUAL ? 2 : 1;
    constexpr int WCH = NOUT * KH * 4 / 16;
    __shared__ uint4 wlds[TW * WCH];

    int tid = threadIdx.x;
    int lane = tid & 63, wid = tid >> 6;
    int tow = DUAL ? 0 : blockIdx.y;
    int aoff = tow * AOFFM;

    {
        const uint4* w0 = (const uint4*)(tow ? a.Wv : a.Wm);
        for (int i = tid; i < WCH; i += 256) wlds[i] = w0[i];
        if (DUAL) {
            const uint4* w1 = (const uint4*)a.Wv;
            for (int i = tid; i < WCH; i += 256) wlds[WCH + i] = w1[i];
        }
    }

    int r15 = lane & 15, kseg = lane >> 4;
    int m0 = blockIdx.x * 128 + wid * 32;
    size_t ar0 = (size_t)(m0 + r15);
    size_t ar1 = (size_t)(m0 + 16 + r15);

    short8 af[2][NK];
#pragma unroll
    for (int ks = 0; ks < NK; ++ks) {
        int kc = ks * 32 + kseg * 8;
        af[0][ks] = (kc < KH) ? *(const short8*)(a.A1 + ar0 * ASTR + aoff + kc)
                              : *(const short8*)(a.A2 + ar0 * ASTR + aoff + (kc - KH));
        af[1][ks] = (kc < KH) ? *(const short8*)(a.A1 + ar1 * ASTR + aoff + kc)
                              : *(const short8*)(a.A2 + ar1 * ASTR + aoff + (kc - KH));
    }
    __syncthreads();

    f32x4 acc[TW][2][NT];
#pragma unroll
    for (int tt = 0; tt < TW; ++tt)
#pragma unroll
        for (int t = 0; t < 2; ++t)
#pragma unroll
            for (int nt = 0; nt < NT; ++nt) acc[tt][t][nt] = (f32x4){0.f, 0.f, 0.f, 0.f};

#pragma unroll
    for (int ks = 0; ks < NK; ++ks) {
#pragma unroll
        for (int nt = 0; nt < NT; ++nt) {
#pragma unroll
            for (int tt = 0; tt < TW; ++tt) {
                short8 w = *(const short8*)&wlds[tt * WCH + (ks * NT + nt) * 64 + lane];
                acc[tt][0][nt] = __builtin_amdgcn_mfma_f32_16x16x32_bf16(af[0][ks], w, acc[tt][0][nt], 0, 0, 0);
                acc[tt][1][nt] = __builtin_amdgcn_mfma_f32_16x16x32_bf16(af[1][ks], w, acc[tt][1][nt], 0, 0, 0);
            }
        }
    }

#pragma unroll
    for (int tt = 0; tt < TW; ++tt) {
        int tsel = DUAL ? tt : tow;
        int ooff = tsel * OOFFM;
        const float* bl = tsel ? a.blv : a.blm;
#pragma unroll
        for (int nt = 0; nt < NT; ++nt) {
            float bb = bl[nt * 16 + r15];
#pragma unroll
            for (int t = 0; t < 2; ++t)
#pragma unroll
                for (int r = 0; r < 4; ++r) acc[tt][t][nt][r] += bb;
        }
        if (DO_LN) {
            const float* g = tsel ? a.gv : a.gm;
            const float* b = tsel ? a.bbv : a.bbm;
#pragma unroll
            for (int t = 0; t < 2; ++t) {
                float s[4] = {0, 0, 0, 0}, q[4] = {0, 0, 0, 0};
#pragma unroll
                for (int nt = 0; nt < NT; ++nt)
#pragma unroll
                    for (int r = 0; r < 4; ++r) { float v = acc[tt][t][nt][r]; s[r] += v; q[r] += v * v; }
#pragma unroll
                for (int off = 1; off < 16; off <<= 1)
#pragma unroll
                    for (int r = 0; r < 4; ++r) { s[r] += __shfl_xor(s[r], off); q[r] += __shfl_xor(q[r], off); }
                float mean[4], rstd[4];
#pragma unroll
                for (int r = 0; r < 4; ++r) {
                    mean[r] = s[r] * (1.0f / NOUT);
                    float var = q[r] * (1.0f / NOUT) - mean[r] * mean[r];
                    rstd[r] = rsqrtf(var + 1e-5f);
                }
                ushort* out = (ushort*)a.out;
#pragma unroll
                for (int nt = 0; nt < NT; ++nt) {
                    int n = nt * 16 + r15;
                    float gg = g[n], bb = b[n];
#pragma unroll
                    for (int r = 0; r < 4; ++r) {
                        int row = m0 + t * 16 + kseg * 4 + r;
                        if (row < NN) {
                            float y = fmaxf((acc[tt][t][nt][r] - mean[r]) * rstd[r] * gg + bb, 0.0f);
                            out[(size_t)row * OSTR + ooff + n] = f2b(y);
                        }
                    }
                }
            }
        } else {
            float* out = (float*)a.out;
#pragma unroll
            for (int t = 0; t < 2; ++t)
#pragma unroll
                for (int nt = 0; nt < NT; ++nt) {
                    int n = nt * 16 + r15;
#pragma unroll
                    for (int r = 0; r < 4; ++r) {
                        int row = m0 + t * 16 + kseg * 4 + r;
                        if (row < NN) out[(size_t)row * OSTR + ooff + n] = acc[tt][t][nt][r];
                    }
                }
        }
    }
}

// ================= layer-2 split kernels (linearity) =================
// <false>: p2[node][tow*64+n] = bf16( h2p_tower @ Wl2^T )
// <true> : out[node][n] = h2p_tower @ Wr2^T + bl[n] + a2[node][tow*64+n]

struct G2Args {
    const ushort *A, *Wm, *Wv, *a2;
    const float *blm, *blv;
    void *outm, *outv;
};

template <bool FINAL>
__global__ __launch_bounds__(256, 2) void k_gemm2(G2Args a) {
    constexpr int NT = 4, NK = 4;
    constexpr int WCH = 1024;  // 16KB
    __shared__ uint4 wlds[WCH];

    int tid = threadIdx.x;
    int lane = tid & 63, wid = tid >> 6;
    int tow = blockIdx.y;
    {
        const uint4* w0 = (const uint4*)(tow ? a.Wv : a.Wm);
        for (int i = tid; i < WCH; i += 256) wlds[i] = w0[i];
    }
    int r15 = lane & 15, kseg = lane >> 4;
    int m0 = blockIdx.x * 128 + wid * 32;
    size_t ar0 = (size_t)(m0 + r15);
    size_t ar1 = (size_t)(m0 + 16 + r15);
    int aoff = tow * 128;

    short8 af[2][NK];
#pragma unroll
    for (int ks = 0; ks < NK; ++ks) {
        int kc = ks * 32 + kseg * 8;
        af[0][ks] = *(const short8*)(a.A + ar0 * 256 + aoff + kc);
        af[1][ks] = *(const short8*)(a.A + ar1 * 256 + aoff + kc);
    }
    __syncthreads();

    f32x4 acc[2][NT];
#pragma unroll
    for (int t = 0; t < 2; ++t)
#pragma unroll
        for (int nt = 0; nt < NT; ++nt) acc[t][nt] = (f32x4){0.f, 0.f, 0.f, 0.f};

#pragma unroll
    for (int ks = 0; ks < NK; ++ks) {
#pragma unroll
        for (int nt = 0; nt < NT; ++nt) {
            short8 w = *(const short8*)&wlds[(ks * NT + nt) * 64 + lane];
            acc[0][nt] = __builtin_amdgcn_mfma_f32_16x16x32_bf16(af[0][ks], w, acc[0][nt], 0, 0, 0);
            acc[1][nt] = __builtin_amdgcn_mfma_f32_16x16x32_bf16(af[1][ks], w, acc[1][nt], 0, 0, 0);
        }
    }

    if (FINAL) {
        const float* bl = tow ? a.blv : a.blm;
        float* out = (float*)(tow ? a.outv : a.outm);
#pragma unroll
        for (int t = 0; t < 2; ++t)
#pragma unroll
            for (int nt = 0; nt < NT; ++nt) {
                int n = nt * 16 + r15;
                float bb = bl[n];
#pragma unroll
                for (int r = 0; r < 4; ++r) {
                    int row = m0 + t * 16 + kseg * 4 + r;
                    if (row < NN) {
                        float av = blo((uint)a.a2[(size_t)row * 128 + tow * 64 + n]);
                        out[(size_t)row * 64 + n] = acc[t][nt][r] + bb + av;
                    }
                }
            }
    } else {
        ushort* out = (ushort*)a.outm;
#pragma unroll
        for (int t = 0; t < 2; ++t)
#pragma unroll
            for (int nt = 0; nt < NT; ++nt) {
                int n = nt * 16 + r15;
#pragma unroll
                for (int r = 0; r < 4; ++r) {
                    int row = m0 + t * 16 + kseg * 4 + r;
                    if (row < NN) out[(size_t)row * 128 + tow * 64 + n] = f2b(acc[t][nt][r]);
                }
            }
    }
}

// ================= launch =================

extern "C" void kernel_launch(void* const* d_in, const int* in_sizes, int n_in,
                              void* d_out, int out_size, void* d_ws, size_t ws_size,
                              hipStream_t stream) {
    const float* x = (const float*)d_in[0];
    const int* ei = (const int*)d_in[1];
    const int* esrc = ei;
    const int* edst = ei + NE;

    const float* mWl0 = (const float*)d_in[2];
    const float* mbl0 = (const float*)d_in[3];
    const float* mWr0 = (const float*)d_in[4];
    const float* mg0  = (const float*)d_in[5];
    const float* mb0  = (const float*)d_in[6];
    const float* mWl1 = (const float*)d_in[7];
    const float* mbl1 = (const float*)d_in[8];
    const float* mWr1 = (const float*)d_in[9];
    const float* mg1  = (const float*)d_in[10];
    const float* mb1  = (const float*)d_in[11];
    const float* mWl2 = (const float*)d_in[12];
    const float* mbl2 = (const float*)d_in[13];
    const float* mWr2 = (const float*)d_in[14];
    const float* vWl0 = (const float*)d_in[15];
    const float* vbl0 = (const float*)d_in[16];
    const float* vWr0 = (const float*)d_in[17];
    const float* vg0  = (const float*)d_in[18];
    const float* vb0  = (const float*)d_in[19];
    const float* vWl1 = (const float*)d_in[20];
    const float* vbl1 = (const float*)d_in[21];
    const float* vWr1 = (const float*)d_in[22];
    const float* vg1  = (const float*)d_in[23];
    const float* vb1  = (const float*)d_in[24];
    const float* vWl2 = (const float*)d_in[25];
    const float* vbl2 = (const float*)d_in[26];
    const float* vWr2 = (const float*)d_in[27];

    char* p = (char*)d_ws;
    auto alloc = [&](size_t bytes) {
        void* r = (void*)p;
        p += (bytes + 255) & ~(size_t)255;
        return r;
    };
    int* bhist     = (int*)alloc((size_t)FB * NBK * 4);
    int* pairRel   = (int*)alloc((size_t)FB * NBK * 4);
    int* bbase     = (int*)alloc((size_t)(NBK + 1) * 4);
    int* row_start = (int*)alloc((size_t)(NN + 1) * 4);
    float* inv_deg = (float*)alloc((size_t)NN * 4);
    int* col       = (int*)alloc((size_t)NE * 4);
    int2* pairs    = (int2*)alloc((size_t)NE * 8);     // reused as agg0 after F3
    ushort* agg0   = (ushort*)pairs;                    // 6.4MB alias (needs NN*64*2=6.4MB)
    ushort* x_bf   = (ushort*)alloc((size_t)MPAD * 64 * 2);
    ushort* h1p    = (ushort*)alloc((size_t)MPAD * 256 * 2);
    ushort* h2p    = (ushort*)alloc((size_t)MPAD * 256 * 2);
    ushort* aggp   = (ushort*)alloc((size_t)MPAD * 256 * 2);  // reused: p2 = first half, a2 = second half
    ushort* p2     = aggp;
    ushort* a2     = aggp + (size_t)MPAD * 128;
    ushort* wc0    = (ushort*)alloc((size_t)128 * 128 * 2);
    ushort* wc1    = (ushort*)alloc((size_t)128 * 256 * 2);
    ushort* wc2    = (ushort*)alloc((size_t)64 * 128 * 2);
    ushort* wc3    = (ushort*)alloc((size_t)128 * 128 * 2);
    ushort* wc4    = (ushort*)alloc((size_t)128 * 256 * 2);
    ushort* wc5    = (ushort*)alloc((size_t)64 * 128 * 2);
    ushort* wc6    = (ushort*)alloc((size_t)64 * 128 * 2);
    ushort* wc7    = (ushort*)alloc((size_t)64 * 128 * 2);

    float* out_mu = (float*)d_out;
    float* out_lv = (float*)d_out + (size_t)NN * 64;

    // conversions (independent of CSR)
    k_xcvt<<<(NN * 64 / 2 + 255) / 256, 256, 0, stream>>>(x, x_bf, NN * 64 / 2);
    W2Args wa;
    wa.srcA[0] = mWl0; wa.srcB[0] = mWr0; wa.dst[0] = wc0;
    wa.srcA[1] = mWl1; wa.srcB[1] = mWr1; wa.dst[1] = wc1;
    wa.srcA[2] = mWl2; wa.srcB[2] = nullptr; wa.dst[2] = wc2;
    wa.srcA[3] = nullptr; wa.srcB[3] = mWr2; wa.dst[3] = wc6;
    wa.srcA[4] = vWl0; wa.srcB[4] = vWr0; wa.dst[4] = wc3;
    wa.srcA[5] = vWl1; wa.srcB[5] = vWr1; wa.dst[5] = wc4;
    wa.srcA[6] = vWl2; wa.srcB[6] = nullptr; wa.dst[6] = wc5;
    wa.srcA[7] = nullptr; wa.srcB[7] = vWr2; wa.dst[7] = wc7;
    k_wcvt<<<512, 256, 0, stream>>>(wa);

    // bucketed CSR build
    k_f1<<<FB, 256, 0, stream>>>(edst, bhist);
    k_fscan<<<1, 256, 0, stream>>>(bhist, pairRel, bbase);
    k_f2<<<FB, 256, 0, stream>>>(esrc, edst, pairRel, bbase, pairs);
    k_f3<<<196, 256, 0, stream>>>(pairs, bbase, row_start, inv_deg, col);

    const int gA16 = (NN * 16 + 255) / 256;   // 3125
    const int gA32 = (NN * 32 + 255) / 256;   // 6250
    const int gM = MPAD / 128;                // 391

    // layer 0: shared agg of x; DUAL GEMM -> packed h1p
    k_agg<64><<<gA16, 256, 0, stream>>>(x_bf, row_start, col, inv_deg, agg0);
    {
        GArgs ga = {agg0, x_bf, wc0, wc3, mbl0, vbl0, mg0, vg0, mb0, vb0, h1p};
        k_gemm<64, 128, true, true, 64, 0, 256, 128><<<dim3(gM, 1), 256, 0, stream>>>(ga);
    }
    // layer 1: single packed agg pass, then packed GEMM -> h2p
    k_agg256<<<gA32, 256, 0, stream>>>(h1p, row_start, col, inv_deg, aggp);
    {
        GArgs ga = {aggp, h1p, wc1, wc4, mbl1, vbl1, mg1, vg1, mb1, vb1, h2p};
        k_gemm<128, 128, true, false, 256, 128, 256, 128><<<dim3(gM, 2), 256, 0, stream>>>(ga);
    }
    // layer 2 via linearity: project (Wl) -> single agg -> final (Wr + agg + bias)
    {
        G2Args g2 = {h2p, wc2, wc5, nullptr, nullptr, nullptr, p2, nullptr};
        k_gemm2<false><<<dim3(gM, 2), 256, 0, stream>>>(g2);
    }
    k_agg<128><<<gA16, 256, 0, stream>>>(p2, row_start, col, inv_deg, a2);
    {
        G2Args g2 = {h2p, wc6, wc7, a2, mbl2, vbl2, out_mu, out_lv};
        k_gemm2<true><<<dim3(gM, 2), 256, 0, stream>>>(g2);
    }
}